// Round 5
// baseline (320.193 us; speedup 1.0000x reference)
//
#include <hip/hip_runtime.h>

typedef unsigned short u16;
typedef __attribute__((ext_vector_type(8))) short short8;
typedef __attribute__((ext_vector_type(4))) float floatx4;

#define DEVI static __device__ __forceinline__

DEVI float bf2f(u16 u) {
  union { unsigned u; float f; } x; x.u = ((unsigned)u) << 16; return x.f;
}
DEVI u16 f2bf(float f) {
  union { float f; unsigned u; } x; x.f = f;
  unsigned r = x.u + 0x7fffu + ((x.u >> 16) & 1u);  // RNE
  return (u16)(r >> 16);
}

// async global->LDS, 16 B per lane, wave-uniform LDS base (dest = base + lane*16)
typedef __attribute__((address_space(1))) const void gas_t;
typedef __attribute__((address_space(3))) void las_t;
DEVI void glds16(const void* g, void* l) {
  __builtin_amdgcn_global_load_lds((gas_t*)g, (las_t*)l, 16, 0, 0);
}

#define BM 128
#define BN 128
#define BK 32

// ---- workspace layouts ----
// 128x32 panels (dense GEMM: ctx, Wd_t): tile (rb,kb) contiguous at
//   ((rb*(K/32))+kb)*4096 u16, elem (r,k) -> r*32 + (k&31).
// 128x64 SWIZZLED panels (QKV GEMM: hidden_bf, Wqkv_t): tile (rb,kt) at
//   ((rb*(K/64))+kt)*8192 u16, elem (r,c) -> r*64 + ((c&63) ^ ((r&7)<<3)).
//   Swizzle baked into global data; glds16 stays linear; ds_read applies the
//   same XOR -> bank-conflict-free at 128B row stride (verified 0 conflicts
//   in round 1). 16B-granular XOR keeps float4/ushort4 runs contiguous.
// Q: row-major [head][t][128].
// K flash tiles: elem (h,t,d) ->
//   h*262144 + (t>>6)*8192 + (d>>5)*2048 + (t&63)*32 + (d&31)
// V flash tiles: elem (h,t,d) ->
//   h*262144 + (t>>6)*8192 + ((t&63)>>5)*4096 + d*32 + (t&31)
//
// NOTE (round-3 lesson): no transcendentals / heavy control flow in GEMM
// epilogues while 16 floatx4 accumulators are live -> scratch spill (2.7 GB
// writes, 67us -> 450us). RoPE stays a standalone kernel.

// ---------------- legacy 128x128 BK=32 GEMM (fallback path only) -----------
__global__ __launch_bounds__(256)
void gemm_kernel(const void* __restrict__ Av, const void* __restrict__ Bv,
                 int K, int lda, int ldb,
                 long sAz, long sBz, int mode, int head0, int aF32, int bF32,
                 const float* __restrict__ bias,
                 u16* __restrict__ out0, u16* __restrict__ out1,
                 u16* __restrict__ out2, float* __restrict__ outf)
{
  const int bn = blockIdx.x, bm = blockIdx.y, z = blockIdx.z;
  const int m0 = bm * BM, n0 = bn * BN;
  const int nkb = K >> 5;

  const float* Af = (const float*)Av;
  const u16*   Ab = (const u16*)Av + (long)z * sAz;
  const float* Bf = (const float*)Bv;
  const u16*   Bb = (const u16*)Bv + (long)z * sBz;

  __shared__ __align__(16) u16 As[BM * BK];   // [m][k] bf16
  __shared__ __align__(16) u16 Bs[BN * BK];   // [n][k] bf16

  const int tid  = threadIdx.x;
  const int lane = tid & 63;
  const int wave = tid >> 6;
  const int wm   = (wave & 1) * 64;
  const int wn   = (wave >> 1) * 64;
  const int lr   = lane & 15;
  const int quad = lane >> 4;

  floatx4 acc[4][4];
  #pragma unroll
  for (int i = 0; i < 4; i++)
    #pragma unroll
    for (int j = 0; j < 4; j++)
      acc[i][j] = floatx4{0.f, 0.f, 0.f, 0.f};

  for (int kb = 0; kb < nkb; kb++) {
    const int k0 = kb * BK;
    __syncthreads();
    if (aF32) {
      #pragma unroll
      for (int L = tid; L < 1024; L += 256) {
        int row = L >> 3, c4 = (L & 7) * 4;
        float4 v = *(const float4*)(Af + (long)(m0 + row) * lda + k0 + c4);
        ushort4 p;
        p.x = f2bf(v.x); p.y = f2bf(v.y); p.z = f2bf(v.z); p.w = f2bf(v.w);
        *(ushort4*)(&As[row * BK + c4]) = p;
      }
    } else {
      const u16* At = Ab + ((long)bm * nkb + kb) * 4096;
      #pragma unroll
      for (int it = 0; it < 2; it++) {
        int Cb = (wave * 2 + it) * 64;
        glds16(At + (long)(Cb + lane) * 8, &As[Cb * 8]);
      }
    }
    if (bF32) {
      #pragma unroll
      for (int L = tid; L < 1024; L += 256) {
        int kr = L >> 5, n4 = (L & 31) * 4;
        float4 v = *(const float4*)(Bf + (long)(k0 + kr) * ldb + n0 + n4);
        Bs[(n4 + 0) * BK + kr] = f2bf(v.x);
        Bs[(n4 + 1) * BK + kr] = f2bf(v.y);
        Bs[(n4 + 2) * BK + kr] = f2bf(v.z);
        Bs[(n4 + 3) * BK + kr] = f2bf(v.w);
      }
    } else {
      const u16* Bt = Bb + ((long)bn * nkb + kb) * 4096;
      #pragma unroll
      for (int it = 0; it < 2; it++) {
        int Cb = (wave * 2 + it) * 64;
        glds16(Bt + (long)(Cb + lane) * 8, &Bs[Cb * 8]);
      }
    }
    __syncthreads();

    short8 af[4], bf[4];
    #pragma unroll
    for (int i = 0; i < 4; i++)
      af[i] = *(const short8*)(&As[(wm + i * 16 + lr) * BK + quad * 8]);
    #pragma unroll
    for (int j = 0; j < 4; j++)
      bf[j] = *(const short8*)(&Bs[(wn + j * 16 + lr) * BK + quad * 8]);
    #pragma unroll
    for (int i = 0; i < 4; i++)
      #pragma unroll
      for (int j = 0; j < 4; j++)
        acc[i][j] = __builtin_amdgcn_mfma_f32_16x16x32_bf16(af[i], bf[j], acc[i][j], 0, 0, 0);
  }

  // epilogue: C/D layout col=lane&15, row=quad*4+reg.
  #pragma unroll
  for (int i = 0; i < 4; i++) {
    #pragma unroll
    for (int j = 0; j < 4; j++) {
      const int col = n0 + wn + j * 16 + lr;
      const int t0  = m0 + wm + i * 16 + quad * 4;   // row for r=0
      if (mode == 0) {
        int head = col / 384;
        int w = col - head * 384;
        long hbase = (long)head * 262144;
        float b = bias[col];
        if (w < 128) {          // Q row-major, pre-scaled by 1/sqrt(128)
          #pragma unroll
          for (int r = 0; r < 4; r++)
            out0[hbase + (long)(t0 + r) * 128 + w] =
                f2bf((acc[i][j][r] + b) * 0.08838834764831845f);
        } else if (w < 256) {   // K flash tiles (t-major inside chunk)
          int d = w - 128;
          long base = hbase + (long)(t0 >> 6) * 8192 + (d >> 5) * 2048 + (d & 31);
          #pragma unroll
          for (int r = 0; r < 4; r++)
            out1[base + ((t0 & 63) + r) * 32] = f2bf(acc[i][j][r] + b);
        } else {                // V flash tiles: r-contiguous -> ushort4
          int d = w - 256;
          long base = hbase + (long)(t0 >> 6) * 8192 + ((t0 & 63) >> 5) * 4096
                    + d * 32 + (t0 & 31);
          ushort4 p;
          p.x = f2bf(acc[i][j][0] + b);
          p.y = f2bf(acc[i][j][1] + b);
          p.z = f2bf(acc[i][j][2] + b);
          p.w = f2bf(acc[i][j][3] + b);
          *(ushort4*)(&out2[base]) = p;
        }
      } else {
        float b = bias[col];
        #pragma unroll
        for (int r = 0; r < 4; r++)
          outf[(long)(t0 + r) * 2048 + col] = acc[i][j][r] + b;
      }
    }
  }
}

// ---------------- QKV GEMM: 128x128 tile, BK=64, swizzled panels -----------
// m97 2-phase structure, but 2 barriers per 64 K-elements instead of per 32:
// halves the vmcnt(0)+lgkmcnt(0) barrier-drain count (the ~20% structural
// stall of this family), doubles MFMA (32) and outstanding DMA (8 glds16/
// thread) per drain. LDS 32 KB single-buffered; occupancy 3 WG/CU (grid).
// Bank-conflict-free ds_read via the r1-verified pre-swizzled panel layout.
__global__ __launch_bounds__(256)
void gemm64_kernel(const u16* __restrict__ Ap, const u16* __restrict__ Bp,
                   int NKT, const float* __restrict__ bias,
                   u16* __restrict__ out0, u16* __restrict__ out1,
                   u16* __restrict__ out2)
{
  const int bn = blockIdx.x, bm = blockIdx.y;
  const int m0 = bm << 7, n0 = bn << 7;

  __shared__ __align__(16) u16 As[128 * 64];   // 16 KB
  __shared__ __align__(16) u16 Bs[128 * 64];   // 16 KB

  const int tid  = threadIdx.x;
  const int lane = tid & 63;
  const int wave = tid >> 6;
  const int wm   = (wave & 1) * 64;
  const int wn   = (wave >> 1) * 64;
  const int lr   = lane & 15;
  const int quad = lane >> 4;
  const int axor = (lr & 7) << 3;            // row-XOR (u16 units, 16B gran)
  const int c0   = (quad * 8) ^ axor;        // k-half 0 swizzled col
  const int c1   = (32 + quad * 8) ^ axor;   // k-half 1 swizzled col

  const u16* At = Ap + (long)bm * NKT * 8192;
  const u16* Bt = Bp + (long)bn * NKT * 8192;

  floatx4 acc[4][4];
  #pragma unroll
  for (int i = 0; i < 4; i++)
    #pragma unroll
    for (int j = 0; j < 4; j++)
      acc[i][j] = floatx4{0.f, 0.f, 0.f, 0.f};

  for (int kt = 0; kt < NKT; kt++) {
    __syncthreads();
    const u16* Ag = At + (long)kt * 8192;
    const u16* Bg = Bt + (long)kt * 8192;
    #pragma unroll
    for (int it = 0; it < 4; it++) {
      int ch = wave * 4 + it;                // 16 chunks x 1 KB per tile
      glds16(Ag + ch * 512 + lane * 8, &As[ch * 512]);
      glds16(Bg + ch * 512 + lane * 8, &Bs[ch * 512]);
    }
    __syncthreads();

    short8 af[4], bf[4];
    // k-half 0
    #pragma unroll
    for (int i = 0; i < 4; i++)
      af[i] = *(const short8*)(&As[(wm + i * 16 + lr) * 64 + c0]);
    #pragma unroll
    for (int j = 0; j < 4; j++)
      bf[j] = *(const short8*)(&Bs[(wn + j * 16 + lr) * 64 + c0]);
    #pragma unroll
    for (int i = 0; i < 4; i++)
      #pragma unroll
      for (int j = 0; j < 4; j++)
        acc[i][j] = __builtin_amdgcn_mfma_f32_16x16x32_bf16(af[i], bf[j], acc[i][j], 0, 0, 0);
    // k-half 1
    #pragma unroll
    for (int i = 0; i < 4; i++)
      af[i] = *(const short8*)(&As[(wm + i * 16 + lr) * 64 + c1]);
    #pragma unroll
    for (int j = 0; j < 4; j++)
      bf[j] = *(const short8*)(&Bs[(wn + j * 16 + lr) * 64 + c1]);
    #pragma unroll
    for (int i = 0; i < 4; i++)
      #pragma unroll
      for (int j = 0; j < 4; j++)
        acc[i][j] = __builtin_amdgcn_mfma_f32_16x16x32_bf16(af[i], bf[j], acc[i][j], 0, 0, 0);
  }

  // epilogue: QKV scatter (+bias). C/D layout col=lane&15, row=quad*4+reg.
  #pragma unroll
  for (int i = 0; i < 4; i++) {
    #pragma unroll
    for (int j = 0; j < 4; j++) {
      const int col = n0 + wn + j * 16 + lr;
      const int t0  = m0 + wm + i * 16 + quad * 4;   // row for r=0
      int head = col / 384;
      int w = col - head * 384;
      long hbase = (long)head * 262144;
      float b = bias[col];
      if (w < 128) {          // Q row-major, pre-scaled by 1/sqrt(128)
        #pragma unroll
        for (int r = 0; r < 4; r++)
          out0[hbase + (long)(t0 + r) * 128 + w] =
              f2bf((acc[i][j][r] + b) * 0.08838834764831845f);
      } else if (w < 256) {   // K flash tiles (t-major inside chunk)
        int d = w - 128;
        long base = hbase + (long)(t0 >> 6) * 8192 + (d >> 5) * 2048 + (d & 31);
        #pragma unroll
        for (int r = 0; r < 4; r++)
          out1[base + ((t0 & 63) + r) * 32] = f2bf(acc[i][j][r] + b);
      } else {                // V flash tiles: r-contiguous -> ushort4
        int d = w - 256;
        long base = hbase + (long)(t0 >> 6) * 8192 + ((t0 & 63) >> 5) * 4096
                  + d * 32 + (t0 & 31);
        ushort4 p;
        p.x = f2bf(acc[i][j][0] + b);
        p.y = f2bf(acc[i][j][1] + b);
        p.z = f2bf(acc[i][j][2] + b);
        p.w = f2bf(acc[i][j][3] + b);
        *(ushort4*)(&out2[base]) = p;
      }
    }
  }
}

// ---------------- dense 128x64 GEMM, 2 WG/CU (ctx @ Wd_t -> out f32) -------
// A = ctx 128x32-panels; B = Wd_t 128x32-panels (64-row sub-panel contiguous).
__global__ __launch_bounds__(256)
void gemm_dense_kernel(const u16* __restrict__ Ap, const u16* __restrict__ Bp,
                       int nkb, const float* __restrict__ bias,
                       float* __restrict__ outf)
{
  const int bn = blockIdx.x, bm = blockIdx.y;
  const int m0 = bm << 7, n0 = bn << 6;

  __shared__ __align__(16) u16 As[128 * 32];   // 8 KB
  __shared__ __align__(16) u16 Bs[64 * 32];    // 4 KB

  const int tid  = threadIdx.x;
  const int lane = tid & 63;
  const int wave = tid >> 6;
  const int wm   = (wave & 1) * 64;
  const int wn   = (wave >> 1) * 32;
  const int lr   = lane & 15;
  const int quad = lane >> 4;

  floatx4 acc[4][2];
  #pragma unroll
  for (int i = 0; i < 4; i++)
    #pragma unroll
    for (int j = 0; j < 2; j++)
      acc[i][j] = floatx4{0.f, 0.f, 0.f, 0.f};

  // B sub-panel base: cols n0..n0+63 of 128-panel (n0>>7), offset (n0&127)*32
  const u16* Bbase = Bp + (long)(n0 >> 7) * nkb * 4096 + (long)(n0 & 127) * 32;

  for (int kb = 0; kb < nkb; kb++) {
    __syncthreads();
    const u16* At = Ap + ((long)bm * nkb + kb) * 4096;
    const u16* Bt = Bbase + (long)kb * 4096;
    #pragma unroll
    for (int it = 0; it < 2; it++) {
      int c = wave * 2 + it;
      glds16(At + c * 512 + lane * 8, &As[c * 512]);
    }
    glds16(Bt + wave * 512 + lane * 8, &Bs[wave * 512]);
    __syncthreads();

    short8 af[4], bf[2];
    #pragma unroll
    for (int i = 0; i < 4; i++)
      af[i] = *(const short8*)(&As[(wm + i * 16 + lr) * 32 + quad * 8]);
    #pragma unroll
    for (int j = 0; j < 2; j++)
      bf[j] = *(const short8*)(&Bs[(wn + j * 16 + lr) * 32 + quad * 8]);
    #pragma unroll
    for (int i = 0; i < 4; i++)
      #pragma unroll
      for (int j = 0; j < 2; j++)
        acc[i][j] = __builtin_amdgcn_mfma_f32_16x16x32_bf16(af[i], bf[j], acc[i][j], 0, 0, 0);
  }

  #pragma unroll
  for (int i = 0; i < 4; i++) {
    #pragma unroll
    for (int j = 0; j < 2; j++) {
      const int col = n0 + wn + j * 16 + lr;
      const int t0  = m0 + wm + i * 16 + quad * 4;
      float b = bias[col];
      #pragma unroll
      for (int r = 0; r < 4; r++)
        outf[(long)(t0 + r) * 2048 + col] = acc[i][j][r] + b;
    }
  }
}

// ---------------- fused flash attention, v6 (XCD-pinned, static-shift, T5) -
__global__ __launch_bounds__(256, 2)
void flash_kernel(const u16* __restrict__ Qg, const u16* __restrict__ Kg,
                  const u16* __restrict__ Vg, u16* __restrict__ ctx)
{
  const int head = blockIdx.x, slot = blockIdx.y;
  const int qb   = (slot < 16) ? slot : 47 - slot;
  const int nkt  = qb + 1;               // 64-row K/V tiles
  const long HS  = 2048L * 128;
  const u16* Qh = Qg + (long)head * HS;
  const u16* Kh = Kg + (long)head * HS;  // flash-tile layout
  const u16* Vh = Vg + (long)head * HS;  // flash-tile layout

  __shared__ __align__(16) u16 k_s[2][8192];   // 2 x 16 KB  [kt][n][32]
  __shared__ __align__(16) u16 v_s[2][8192];   // 2 x 16 KB  [kt2][d][32]
  __shared__ __align__(16) u16 p_s[4 * 1088];  // 8.5 KB, per-wave 16 x stride-68

  const int tid  = threadIdx.x;
  const int lane = tid & 63, wv = tid >> 6;
  const int lr   = lane & 15, quad = lane >> 4;
  const int qs   = qb * 64 + wv * 16;
  const int pbase = wv * 1088;

  short8 qf[4];
  #pragma unroll
  for (int kt = 0; kt < 4; kt++)
    qf[kt] = *(const short8*)(Qh + (long)(qs + lr) * 128 + kt * 32 + quad * 8);

  float l_r[4];
  #pragma unroll
  for (int r = 0; r < 4; r++) l_r[r] = 0.f;

  floatx4 o[8];
  #pragma unroll
  for (int j = 0; j < 8; j++) o[j] = floatx4{0.f, 0.f, 0.f, 0.f};

  // prologue: stage tile 0 into buffer 0 (8 glds16/wave, contiguous bursts)
  #pragma unroll
  for (int it = 0; it < 4; it++) {
    int Cb = (wv * 4 + it) * 64;
    glds16(Kh + (long)(Cb + lane) * 8, &k_s[0][Cb * 8]);
    glds16(Vh + (long)(Cb + lane) * 8, &v_s[0][Cb * 8]);
  }

  for (int kb = 0; kb < nkt; kb++) {
    const int cur = kb & 1;
    __syncthreads();                     // drains own DMA -> buf[cur] ready
    if (kb + 1 < nkt) {                  // prefetch tile kb+1 into buf[cur^1]
      const u16* Kt = Kh + (long)(kb + 1) * 8192;
      const u16* Vt = Vh + (long)(kb + 1) * 8192;
      #pragma unroll
      for (int it = 0; it < 4; it++) {
        int Cb = (wv * 4 + it) * 64;
        glds16(Kt + (long)(Cb + lane) * 8, &k_s[cur ^ 1][Cb * 8]);
        glds16(Vt + (long)(Cb + lane) * 8, &v_s[cur ^ 1][Cb * 8]);
      }
    }

    // S = Q K^T : strip 16 rows x 64 cols
    floatx4 sa[4];
    #pragma unroll
    for (int j = 0; j < 4; j++) sa[j] = floatx4{0.f, 0.f, 0.f, 0.f};
    __builtin_amdgcn_s_setprio(1);
    #pragma unroll
    for (int kt = 0; kt < 4; kt++) {
      #pragma unroll
      for (int j = 0; j < 4; j++) {
        short8 bf = *(const short8*)(&k_s[cur][kt * 2048 + (j * 16 + lr) * 32 + quad * 8]);
        sa[j] = __builtin_amdgcn_mfma_f32_16x16x32_bf16(qf[kt], bf, sa[j], 0, 0, 0);
      }
    }
    __builtin_amdgcn_s_setprio(0);

    if (kb == nkt - 1) {                 // causal mask, last tile only
      #pragma unroll
      for (int j = 0; j < 4; j++)
        #pragma unroll
        for (int r = 0; r < 4; r++) {
          int cg = kb * 64 + j * 16 + lr;
          int rg = qs + quad * 4 + r;
          if (cg > rg) sa[j][r] = -1e30f;
        }
    }

    // static-shift softmax: P = exp(S - 8), l += row-sum (shift-invariant;
    // masked lanes underflow to exactly 0)
    #pragma unroll
    for (int r = 0; r < 4; r++) {
      float s0 = 0.f;
      #pragma unroll
      for (int j = 0; j < 4; j++) {
        float e = __expf(sa[j][r] - 8.f);
        p_s[pbase + (quad * 4 + r) * 68 + j * 16 + lr] = f2bf(e);
        s0 += e;
      }
      s0 += __shfl_xor(s0, 1, 16);
      s0 += __shfl_xor(s0, 2, 16);
      s0 += __shfl_xor(s0, 4, 16);
      s0 += __shfl_xor(s0, 8, 16);
      l_r[r] += s0;
    }

    // PV: O += P x V (same-wave P write->read, no barrier)
    __builtin_amdgcn_s_setprio(1);
    #pragma unroll
    for (int kt2 = 0; kt2 < 2; kt2++) {
      short8 pa = *(const short8*)(&p_s[pbase + lr * 68 + kt2 * 32 + quad * 8]);
      #pragma unroll
      for (int j = 0; j < 8; j++) {
        short8 vb = *(const short8*)(&v_s[cur][kt2 * 4096 + (j * 16 + lr) * 32 + quad * 8]);
        o[j] = __builtin_amdgcn_mfma_f32_16x16x32_bf16(pa, vb, o[j], 0, 0, 0);
      }
    }
    __builtin_amdgcn_s_setprio(0);
  } // kb

  // epilogue -> ctx PANELS: element (row, c), c = head*128 + j*16 + lr.
  #pragma unroll
  for (int r = 0; r < 4; r++) {
    float inv = 1.f / l_r[r];
    int row = qs + quad * 4 + r;
    long prow = ((long)(row >> 7) * 64) * 4096 + (row & 127) * 32;
    #pragma unroll
    for (int j = 0; j < 8; j++) {
      int c = head * 128 + j * 16 + lr;
      ctx[prow + (long)(c >> 5) * 4096 + (c & 31)] = f2bf(o[j][r] * inv);
    }
  }
}

// fp32 [M][K] row-major -> bf16 swizzled 128x64-PANELS. float4/thread.
__global__ __launch_bounds__(256)
void convert64_kernel(const float* __restrict__ in, u16* __restrict__ out,
                      int K, long n4)
{
  long i = (long)blockIdx.x * 256 + threadIdx.x;
  if (i < n4) {
    float4 v = ((const float4*)in)[i];
    ushort4 p;
    p.x = f2bf(v.x); p.y = f2bf(v.y); p.z = f2bf(v.z); p.w = f2bf(v.w);
    long e = i * 4;
    int row = (int)(e / K), k = (int)(e % K);
    long d = ((long)(row >> 7) * (K >> 6) + (k >> 6)) * 8192
           + (row & 127) * 64 + ((k & 63) ^ ((row & 7) << 3));
    *(ushort4*)(&out[d]) = p;   // XOR flips bits>=3; 4-run stays contiguous
  }
}

// fp32 [K][N] -> bf16 swizzled 128x64-PANELS of the [N][K] transpose.
__global__ __launch_bounds__(256)
void transpose64_kernel(const float* __restrict__ in, u16* __restrict__ out,
                        int K, int N)
{
  __shared__ float t[32][33];
  int n0 = blockIdx.x * 32, k0 = blockIdx.y * 32;
  int tx = threadIdx.x & 31, ty = threadIdx.x >> 5;
  #pragma unroll
  for (int i = 0; i < 4; i++)
    t[ty + i * 8][tx] = in[(long)(k0 + ty + i * 8) * N + n0 + tx];
  __syncthreads();
  const int nkt = K >> 6;
  #pragma unroll
  for (int i = 0; i < 4; i++) {
    int n = n0 + ty + i * 8;
    int k = k0 + tx;
    long d = ((long)(n >> 7) * nkt + (k >> 6)) * 8192
           + (n & 127) * 64 + ((k & 63) ^ ((n & 7) << 3));
    out[d] = f2bf(t[tx][ty + i * 8]);
  }
}

// fp32 [K][N] -> bf16 legacy 128x32-PANELS of the [N][K] transpose.
__global__ __launch_bounds__(256)
void transpose_bf16_kernel(const float* __restrict__ in, u16* __restrict__ out,
                           int K, int N)
{
  __shared__ float t[32][33];
  int n0 = blockIdx.x * 32, k0 = blockIdx.y * 32;
  int tx = threadIdx.x & 31, ty = threadIdx.x >> 5;
  #pragma unroll
  for (int i = 0; i < 4; i++)
    t[ty + i * 8][tx] = in[(long)(k0 + ty + i * 8) * N + n0 + tx];
  __syncthreads();
  const int nkb = K >> 5;
  #pragma unroll
  for (int i = 0; i < 4; i++) {
    int n = n0 + ty + i * 8;
    int k = k0 + tx;
    long d = ((long)(n >> 7) * nkb + (k >> 5)) * 4096 + (n & 127) * 32 + (k & 31);
    out[d] = f2bf(t[tx][ty + i * 8]);
  }
}

// RoPE in-place on first 32 dims of Q (row-major) and K (flash tiles).
__global__ __launch_bounds__(256)
void rope_kernel(u16* __restrict__ Q, u16* __restrict__ K)
{
  int idx = blockIdx.x * 256 + threadIdx.x;
  int i = idx & 15;
  int s = (idx >> 4) & 2047;
  int head = (idx >> 15) & 15;
  int isK = (idx >> 19);
  float inv_freq = exp2f(-(float)i * 0.83048202372184058696f); // 10000^(-i/16)
  float ang = (float)s * inv_freq;
  float c = cosf(ang), sn = sinf(ang);
  long b0, b1;
  u16* buf;
  if (isK) {
    buf = K;
    long base = (long)head * 262144 + (long)(s >> 6) * 8192 + (s & 63) * 32;
    b0 = base + i;         // d = i      (kt=0 chunk)
    b1 = base + i + 16;    // d = i+16
  } else {
    buf = Q;
    long base = ((long)head * 2048 + s) * 128;
    b0 = base + i;
    b1 = base + i + 16;
  }
  float x1 = bf2f(buf[b0]);
  float x2 = bf2f(buf[b1]);
  buf[b0] = f2bf(x1 * c - x2 * sn);
  buf[b1] = f2bf(x2 * c + x1 * sn);
}

extern "C" void kernel_launch(void* const* d_in, const int* in_sizes, int n_in,
                              void* d_out, int out_size, void* d_ws, size_t ws_size,
                              hipStream_t stream)
{
  const float* hidden = (const float*)d_in[0];   // [2048][2048] f32
  const float* Wqkv   = (const float*)d_in[1];   // [2048][6144] f32
  const float* bqkv   = (const float*)d_in[2];   // [6144] f32
  const float* Wd     = (const float*)d_in[3];   // [2048][2048] f32
  const float* bd     = (const float*)d_in[4];   // [2048] f32
  float* out = (float*)d_out;                    // [2048][2048] f32

  char* ws = (char*)d_ws;
  u16* Q   = (u16*)(ws);                      //  8 MB  Q row-major
  u16* Kb  = (u16*)(ws + (8ull  << 20));      //  8 MB  K flash tiles
  u16* Vt  = (u16*)(ws + (16ull << 20));      //  8 MB  V flash tiles
  u16* ctx = (u16*)(ws + (24ull << 20));      //  8 MB  ctx panels (128x32)
  char* regA = ws + (32ull << 20);            // overlay region

  const bool fast = ws_size >= (64ull << 20);

  if (fast) {
    u16* hidden_bf = (u16*)(regA);                  // 8 MB 64-panels, then Wd_t
    u16* Wqkv_t    = (u16*)(regA + (8ull << 20));   // 24 MB 64-panels
    u16* Wd_t      = (u16*)(regA);                  // 8 MB 32-panels

    convert64_kernel<<<dim3(4096), 256, 0, stream>>>(hidden, hidden_bf, 2048, 1048576);
    transpose64_kernel<<<dim3(192, 64), 256, 0, stream>>>(Wqkv, Wqkv_t, 2048, 6144);

    gemm64_kernel<<<dim3(48, 16), 256, 0, stream>>>(
        hidden_bf, Wqkv_t, /*NKT*/32, bqkv, Q, Kb, Vt);

    rope_kernel<<<dim3(4096), 256, 0, stream>>>(Q, Kb);
    transpose_bf16_kernel<<<dim3(64, 64), 256, 0, stream>>>(Wd, Wd_t, 2048, 2048);

    flash_kernel<<<dim3(16, 32), 256, 0, stream>>>(Q, Kb, Vt, ctx);

    gemm_dense_kernel<<<dim3(32, 16), 256, 0, stream>>>(
        ctx, Wd_t, /*nkb*/64, bd, out);
  } else {
    // fallback: fp32 in-GEMM staging for QKV; dense uses ctx panels + fp32 Wd
    gemm_kernel<<<dim3(48, 16, 1), 256, 0, stream>>>(
        hidden, Wqkv, 2048, 2048, 6144, 0, 0, /*mode*/0, 0, 1, 1, bqkv,
        Q, Kb, Vt, nullptr);
    rope_kernel<<<dim3(4096), 256, 0, stream>>>(Q, Kb);
    flash_kernel<<<dim3(16, 32), 256, 0, stream>>>(Q, Kb, Vt, ctx);
    gemm_kernel<<<dim3(16, 16, 1), 256, 0, stream>>>(
        ctx, Wd, 2048, 2048, 2048, 0, 0, /*mode*/3, 0, 0, 1, bd,
        nullptr, nullptr, nullptr, out);
  }
}

// Round 6
// 296.201 us; speedup vs baseline: 1.0810x; 1.0810x over previous
//
#include <hip/hip_runtime.h>

typedef unsigned short u16;
typedef __attribute__((ext_vector_type(8))) short short8;
typedef __attribute__((ext_vector_type(4))) float floatx4;

#define DEVI static __device__ __forceinline__

DEVI float bf2f(u16 u) {
  union { unsigned u; float f; } x; x.u = ((unsigned)u) << 16; return x.f;
}
DEVI u16 f2bf(float f) {
  union { float f; unsigned u; } x; x.f = f;
  unsigned r = x.u + 0x7fffu + ((x.u >> 16) & 1u);  // RNE
  return (u16)(r >> 16);
}

// async global->LDS, 16 B per lane, wave-uniform LDS base (dest = base + lane*16)
typedef __attribute__((address_space(1))) const void gas_t;
typedef __attribute__((address_space(3))) void las_t;
DEVI void glds16(const void* g, void* l) {
  __builtin_amdgcn_global_load_lds((gas_t*)g, (las_t*)l, 16, 0, 0);
}

#define BM 128
#define BN 128
#define BK 32

// ---- workspace layouts ----
// 128x32 panels (all GEMM operands): tile (rb,kb) contiguous at
//   ((rb*(K/32))+kb)*4096 u16, elem (r,k) -> r*32 + (k&31).
// Q: row-major [head][t][128].
// K flash tiles: elem (h,t,d) ->
//   h*262144 + (t>>6)*8192 + (d>>5)*2048 + (t&63)*32 + (d&31)
// V flash tiles: elem (h,t,d) ->
//   h*262144 + (t>>6)*8192 + ((t&63)>>5)*4096 + d*32 + (t&31)
//
// Lessons pinned: (r3) no transcendentals in register-fat GEMM epilogues ->
// scratch spill. (r1/r2) 256x256 8-phase does not beat m97 here (192 WGs,
// FETCH x2). (r5) BK=64 regresses (FETCH +31%, occupancy down). QKV GEMM
// stays the round-0 m97 structure.

// Epilogue modes: 0 = QKV (+bias, scatter Q/K/V), 3 = dense (+bias, f32 out)
__global__ __launch_bounds__(256)
void gemm_kernel(const void* __restrict__ Av, const void* __restrict__ Bv,
                 int K, int lda, int ldb,
                 long sAz, long sBz, int mode, int head0, int aF32, int bF32,
                 const float* __restrict__ bias,
                 u16* __restrict__ out0, u16* __restrict__ out1,
                 u16* __restrict__ out2, float* __restrict__ outf)
{
  const int bn = blockIdx.x, bm = blockIdx.y, z = blockIdx.z;
  const int m0 = bm * BM, n0 = bn * BN;
  const int nkb = K >> 5;

  const float* Af = (const float*)Av;
  const u16*   Ab = (const u16*)Av + (long)z * sAz;
  const float* Bf = (const float*)Bv;
  const u16*   Bb = (const u16*)Bv + (long)z * sBz;

  __shared__ __align__(16) u16 As[BM * BK];   // [m][k] bf16
  __shared__ __align__(16) u16 Bs[BN * BK];   // [n][k] bf16

  const int tid  = threadIdx.x;
  const int lane = tid & 63;
  const int wave = tid >> 6;
  const int wm   = (wave & 1) * 64;
  const int wn   = (wave >> 1) * 64;
  const int lr   = lane & 15;
  const int quad = lane >> 4;

  floatx4 acc[4][4];
  #pragma unroll
  for (int i = 0; i < 4; i++)
    #pragma unroll
    for (int j = 0; j < 4; j++)
      acc[i][j] = floatx4{0.f, 0.f, 0.f, 0.f};

  for (int kb = 0; kb < nkb; kb++) {
    const int k0 = kb * BK;
    __syncthreads();
    if (aF32) {
      #pragma unroll
      for (int L = tid; L < 1024; L += 256) {
        int row = L >> 3, c4 = (L & 7) * 4;
        float4 v = *(const float4*)(Af + (long)(m0 + row) * lda + k0 + c4);
        ushort4 p;
        p.x = f2bf(v.x); p.y = f2bf(v.y); p.z = f2bf(v.z); p.w = f2bf(v.w);
        *(ushort4*)(&As[row * BK + c4]) = p;
      }
    } else {
      const u16* At = Ab + ((long)bm * nkb + kb) * 4096;
      #pragma unroll
      for (int it = 0; it < 2; it++) {
        int Cb = (wave * 2 + it) * 64;
        glds16(At + (long)(Cb + lane) * 8, &As[Cb * 8]);
      }
    }
    if (bF32) {
      #pragma unroll
      for (int L = tid; L < 1024; L += 256) {
        int kr = L >> 5, n4 = (L & 31) * 4;
        float4 v = *(const float4*)(Bf + (long)(k0 + kr) * ldb + n0 + n4);
        Bs[(n4 + 0) * BK + kr] = f2bf(v.x);
        Bs[(n4 + 1) * BK + kr] = f2bf(v.y);
        Bs[(n4 + 2) * BK + kr] = f2bf(v.z);
        Bs[(n4 + 3) * BK + kr] = f2bf(v.w);
      }
    } else {
      const u16* Bt = Bb + ((long)bn * nkb + kb) * 4096;
      #pragma unroll
      for (int it = 0; it < 2; it++) {
        int Cb = (wave * 2 + it) * 64;
        glds16(Bt + (long)(Cb + lane) * 8, &Bs[Cb * 8]);
      }
    }
    __syncthreads();

    short8 af[4], bf[4];
    #pragma unroll
    for (int i = 0; i < 4; i++)
      af[i] = *(const short8*)(&As[(wm + i * 16 + lr) * BK + quad * 8]);
    #pragma unroll
    for (int j = 0; j < 4; j++)
      bf[j] = *(const short8*)(&Bs[(wn + j * 16 + lr) * BK + quad * 8]);
    #pragma unroll
    for (int i = 0; i < 4; i++)
      #pragma unroll
      for (int j = 0; j < 4; j++)
        acc[i][j] = __builtin_amdgcn_mfma_f32_16x16x32_bf16(af[i], bf[j], acc[i][j], 0, 0, 0);
  }

  // epilogue: C/D layout col=lane&15, row=quad*4+reg. In mode 0 each
  // 128-col block is purely Q, K, or V (384 = 3*128) with one head.
  #pragma unroll
  for (int i = 0; i < 4; i++) {
    #pragma unroll
    for (int j = 0; j < 4; j++) {
      const int col = n0 + wn + j * 16 + lr;
      const int t0  = m0 + wm + i * 16 + quad * 4;   // row for r=0
      if (mode == 0) {
        int head = col / 384;
        int w = col - head * 384;
        long hbase = (long)head * 262144;
        float b = bias[col];
        if (w < 128) {          // Q row-major, pre-scaled by 1/sqrt(128)
          #pragma unroll
          for (int r = 0; r < 4; r++)
            out0[hbase + (long)(t0 + r) * 128 + w] =
                f2bf((acc[i][j][r] + b) * 0.08838834764831845f);
        } else if (w < 256) {   // K flash tiles (t-major inside chunk)
          int d = w - 128;
          long base = hbase + (long)(t0 >> 6) * 8192 + (d >> 5) * 2048 + (d & 31);
          #pragma unroll
          for (int r = 0; r < 4; r++)
            out1[base + ((t0 & 63) + r) * 32] = f2bf(acc[i][j][r] + b);
        } else {                // V flash tiles: r-contiguous -> ushort4
          int d = w - 256;
          long base = hbase + (long)(t0 >> 6) * 8192 + ((t0 & 63) >> 5) * 4096
                    + d * 32 + (t0 & 31);
          ushort4 p;
          p.x = f2bf(acc[i][j][0] + b);
          p.y = f2bf(acc[i][j][1] + b);
          p.z = f2bf(acc[i][j][2] + b);
          p.w = f2bf(acc[i][j][3] + b);
          *(ushort4*)(&out2[base]) = p;
        }
      } else {
        float b = bias[col];
        #pragma unroll
        for (int r = 0; r < 4; r++)
          outf[(long)(t0 + r) * 2048 + col] = acc[i][j][r] + b;
      }
    }
  }
}

// ---------------- dense 128x64 GEMM, 2 WG/CU (ctx @ Wd_t -> out f32) -------
// A = ctx 128x32-panels; B = Wd_t 128x32-panels (64-row sub-panel contiguous).
__global__ __launch_bounds__(256)
void gemm_dense_kernel(const u16* __restrict__ Ap, const u16* __restrict__ Bp,
                       int nkb, const float* __restrict__ bias,
                       float* __restrict__ outf)
{
  const int bn = blockIdx.x, bm = blockIdx.y;
  const int m0 = bm << 7, n0 = bn << 6;

  __shared__ __align__(16) u16 As[128 * 32];   // 8 KB
  __shared__ __align__(16) u16 Bs[64 * 32];    // 4 KB

  const int tid  = threadIdx.x;
  const int lane = tid & 63;
  const int wave = tid >> 6;
  const int wm   = (wave & 1) * 64;
  const int wn   = (wave >> 1) * 32;
  const int lr   = lane & 15;
  const int quad = lane >> 4;

  floatx4 acc[4][2];
  #pragma unroll
  for (int i = 0; i < 4; i++)
    #pragma unroll
    for (int j = 0; j < 2; j++)
      acc[i][j] = floatx4{0.f, 0.f, 0.f, 0.f};

  // B sub-panel base: cols n0..n0+63 of 128-panel (n0>>7), offset (n0&127)*32
  const u16* Bbase = Bp + (long)(n0 >> 7) * nkb * 4096 + (long)(n0 & 127) * 32;

  for (int kb = 0; kb < nkb; kb++) {
    __syncthreads();
    const u16* At = Ap + ((long)bm * nkb + kb) * 4096;
    const u16* Bt = Bbase + (long)kb * 4096;
    #pragma unroll
    for (int it = 0; it < 2; it++) {
      int c = wave * 2 + it;
      glds16(At + c * 512 + lane * 8, &As[c * 512]);
    }
    glds16(Bt + wave * 512 + lane * 8, &Bs[wave * 512]);
    __syncthreads();

    short8 af[4], bf[2];
    #pragma unroll
    for (int i = 0; i < 4; i++)
      af[i] = *(const short8*)(&As[(wm + i * 16 + lr) * 32 + quad * 8]);
    #pragma unroll
    for (int j = 0; j < 2; j++)
      bf[j] = *(const short8*)(&Bs[(wn + j * 16 + lr) * 32 + quad * 8]);
    #pragma unroll
    for (int i = 0; i < 4; i++)
      #pragma unroll
      for (int j = 0; j < 2; j++)
        acc[i][j] = __builtin_amdgcn_mfma_f32_16x16x32_bf16(af[i], bf[j], acc[i][j], 0, 0, 0);
  }

  #pragma unroll
  for (int i = 0; i < 4; i++) {
    #pragma unroll
    for (int j = 0; j < 2; j++) {
      const int col = n0 + wn + j * 16 + lr;
      const int t0  = m0 + wm + i * 16 + quad * 4;
      float b = bias[col];
      #pragma unroll
      for (int r = 0; r < 4; r++)
        outf[(long)(t0 + r) * 2048 + col] = acc[i][j][r] + b;
    }
  }
}

// ---------------- fused flash attention, v6 (XCD-pinned, static-shift, T5) -
__global__ __launch_bounds__(256, 2)
void flash_kernel(const u16* __restrict__ Qg, const u16* __restrict__ Kg,
                  const u16* __restrict__ Vg, u16* __restrict__ ctx)
{
  const int head = blockIdx.x, slot = blockIdx.y;
  const int qb   = (slot < 16) ? slot : 47 - slot;
  const int nkt  = qb + 1;               // 64-row K/V tiles
  const long HS  = 2048L * 128;
  const u16* Qh = Qg + (long)head * HS;
  const u16* Kh = Kg + (long)head * HS;  // flash-tile layout
  const u16* Vh = Vg + (long)head * HS;  // flash-tile layout

  __shared__ __align__(16) u16 k_s[2][8192];   // 2 x 16 KB  [kt][n][32]
  __shared__ __align__(16) u16 v_s[2][8192];   // 2 x 16 KB  [kt2][d][32]
  __shared__ __align__(16) u16 p_s[4 * 1088];  // 8.5 KB, per-wave 16 x stride-68

  const int tid  = threadIdx.x;
  const int lane = tid & 63, wv = tid >> 6;
  const int lr   = lane & 15, quad = lane >> 4;
  const int qs   = qb * 64 + wv * 16;
  const int pbase = wv * 1088;

  short8 qf[4];
  #pragma unroll
  for (int kt = 0; kt < 4; kt++)
    qf[kt] = *(const short8*)(Qh + (long)(qs + lr) * 128 + kt * 32 + quad * 8);

  float l_r[4];
  #pragma unroll
  for (int r = 0; r < 4; r++) l_r[r] = 0.f;

  floatx4 o[8];
  #pragma unroll
  for (int j = 0; j < 8; j++) o[j] = floatx4{0.f, 0.f, 0.f, 0.f};

  // prologue: stage tile 0 into buffer 0 (8 glds16/wave, contiguous bursts)
  #pragma unroll
  for (int it = 0; it < 4; it++) {
    int Cb = (wv * 4 + it) * 64;
    glds16(Kh + (long)(Cb + lane) * 8, &k_s[0][Cb * 8]);
    glds16(Vh + (long)(Cb + lane) * 8, &v_s[0][Cb * 8]);
  }

  for (int kb = 0; kb < nkt; kb++) {
    const int cur = kb & 1;
    __syncthreads();                     // drains own DMA -> buf[cur] ready
    if (kb + 1 < nkt) {                  // prefetch tile kb+1 into buf[cur^1]
      const u16* Kt = Kh + (long)(kb + 1) * 8192;
      const u16* Vt = Vh + (long)(kb + 1) * 8192;
      #pragma unroll
      for (int it = 0; it < 4; it++) {
        int Cb = (wv * 4 + it) * 64;
        glds16(Kt + (long)(Cb + lane) * 8, &k_s[cur ^ 1][Cb * 8]);
        glds16(Vt + (long)(Cb + lane) * 8, &v_s[cur ^ 1][Cb * 8]);
      }
    }

    // S = Q K^T : strip 16 rows x 64 cols
    floatx4 sa[4];
    #pragma unroll
    for (int j = 0; j < 4; j++) sa[j] = floatx4{0.f, 0.f, 0.f, 0.f};
    __builtin_amdgcn_s_setprio(1);
    #pragma unroll
    for (int kt = 0; kt < 4; kt++) {
      #pragma unroll
      for (int j = 0; j < 4; j++) {
        short8 bf = *(const short8*)(&k_s[cur][kt * 2048 + (j * 16 + lr) * 32 + quad * 8]);
        sa[j] = __builtin_amdgcn_mfma_f32_16x16x32_bf16(qf[kt], bf, sa[j], 0, 0, 0);
      }
    }
    __builtin_amdgcn_s_setprio(0);

    if (kb == nkt - 1) {                 // causal mask, last tile only
      #pragma unroll
      for (int j = 0; j < 4; j++)
        #pragma unroll
        for (int r = 0; r < 4; r++) {
          int cg = kb * 64 + j * 16 + lr;
          int rg = qs + quad * 4 + r;
          if (cg > rg) sa[j][r] = -1e30f;
        }
    }

    // static-shift softmax: P = exp(S - 8), l += row-sum (shift-invariant;
    // masked lanes underflow to exactly 0)
    #pragma unroll
    for (int r = 0; r < 4; r++) {
      float s0 = 0.f;
      #pragma unroll
      for (int j = 0; j < 4; j++) {
        float e = __expf(sa[j][r] - 8.f);
        p_s[pbase + (quad * 4 + r) * 68 + j * 16 + lr] = f2bf(e);
        s0 += e;
      }
      s0 += __shfl_xor(s0, 1, 16);
      s0 += __shfl_xor(s0, 2, 16);
      s0 += __shfl_xor(s0, 4, 16);
      s0 += __shfl_xor(s0, 8, 16);
      l_r[r] += s0;
    }

    // PV: O += P x V (same-wave P write->read, no barrier)
    __builtin_amdgcn_s_setprio(1);
    #pragma unroll
    for (int kt2 = 0; kt2 < 2; kt2++) {
      short8 pa = *(const short8*)(&p_s[pbase + lr * 68 + kt2 * 32 + quad * 8]);
      #pragma unroll
      for (int j = 0; j < 8; j++) {
        short8 vb = *(const short8*)(&v_s[cur][kt2 * 4096 + (j * 16 + lr) * 32 + quad * 8]);
        o[j] = __builtin_amdgcn_mfma_f32_16x16x32_bf16(pa, vb, o[j], 0, 0, 0);
      }
    }
    __builtin_amdgcn_s_setprio(0);
  } // kb

  // epilogue -> ctx PANELS: element (row, c), c = head*128 + j*16 + lr.
  #pragma unroll
  for (int r = 0; r < 4; r++) {
    float inv = 1.f / l_r[r];
    int row = qs + quad * 4 + r;
    long prow = ((long)(row >> 7) * 64) * 4096 + (row & 127) * 32;
    #pragma unroll
    for (int j = 0; j < 8; j++) {
      int c = head * 128 + j * 16 + lr;
      ctx[prow + (long)(c >> 5) * 4096 + (c & 31)] = f2bf(o[j][r] * inv);
    }
  }
}

// fp32 [M][K] row-major -> bf16 128-PANELS. float4/thread.
__global__ __launch_bounds__(256)
void convert_bf16_kernel(const float* __restrict__ in, u16* __restrict__ out,
                         int K, long n4)
{
  long i = (long)blockIdx.x * 256 + threadIdx.x;
  if (i < n4) {
    float4 v = ((const float4*)in)[i];
    ushort4 p;
    p.x = f2bf(v.x); p.y = f2bf(v.y); p.z = f2bf(v.z); p.w = f2bf(v.w);
    long e = i * 4;
    int row = (int)(e / K), k = (int)(e % K);
    long d = ((long)(row >> 7) * (K >> 5) + (k >> 5)) * 4096
           + (row & 127) * 32 + (k & 31);
    *(ushort4*)(&out[d]) = p;
  }
}

// fp32 [K][N] -> bf16 128-PANELS of the [N][K] transpose. 32x32 tiles.
// v2: coalesced write phase. A 32x32 output tile is ONE contiguous 2048 B
// block of the panel ((n&127)*32 + (k&31), n,k each spanning 32). Thread w
// writes ushort4 at block-offset w*8 (n'=w>>3, k'=(w&7)*4): the WG emits
// 2048 contiguous bytes (vs 64 B bursts before, ~2-3x store efficiency).
// LDS reads t[kp+q][np]: bank = (kp+np)%32 = 4(w&7)+(w>>3) -> all 32
// distinct, conflict-free.
__global__ __launch_bounds__(256)
void transpose_bf16_kernel(const float* __restrict__ in, u16* __restrict__ out,
                           int K, int N)
{
  __shared__ float t[32][33];
  int n0 = blockIdx.x * 32, k0 = blockIdx.y * 32;
  int tx = threadIdx.x & 31, ty = threadIdx.x >> 5;
  #pragma unroll
  for (int i = 0; i < 4; i++)
    t[ty + i * 8][tx] = in[(long)(k0 + ty + i * 8) * N + n0 + tx];  // t[k'][n']
  __syncthreads();
  const int nkb = K >> 5;
  const int w  = threadIdx.x;
  const int np = w >> 3;           // 0..31  (n within tile)
  const int kp = (w & 7) * 4;      // 0..28  (k within tile, quad)
  ushort4 p;
  p.x = f2bf(t[kp + 0][np]);
  p.y = f2bf(t[kp + 1][np]);
  p.z = f2bf(t[kp + 2][np]);
  p.w = f2bf(t[kp + 3][np]);
  const int n = n0 + np, k = k0 + kp;
  long d = ((long)(n >> 7) * nkb + (k >> 5)) * 4096 + (n & 127) * 32 + (k & 31);
  *(ushort4*)(&out[d]) = p;
}

// RoPE in-place on first 32 dims of Q (row-major) and K (flash tiles).
__global__ __launch_bounds__(256)
void rope_kernel(u16* __restrict__ Q, u16* __restrict__ K)
{
  int idx = blockIdx.x * 256 + threadIdx.x;
  int i = idx & 15;
  int s = (idx >> 4) & 2047;
  int head = (idx >> 15) & 15;
  int isK = (idx >> 19);
  float inv_freq = exp2f(-(float)i * 0.83048202372184058696f); // 10000^(-i/16)
  float ang = (float)s * inv_freq;
  float c = cosf(ang), sn = sinf(ang);
  long b0, b1;
  u16* buf;
  if (isK) {
    buf = K;
    long base = (long)head * 262144 + (long)(s >> 6) * 8192 + (s & 63) * 32;
    b0 = base + i;         // d = i      (kt=0 chunk)
    b1 = base + i + 16;    // d = i+16
  } else {
    buf = Q;
    long base = ((long)head * 2048 + s) * 128;
    b0 = base + i;
    b1 = base + i + 16;
  }
  float x1 = bf2f(buf[b0]);
  float x2 = bf2f(buf[b1]);
  buf[b0] = f2bf(x1 * c - x2 * sn);
  buf[b1] = f2bf(x2 * c + x1 * sn);
}

extern "C" void kernel_launch(void* const* d_in, const int* in_sizes, int n_in,
                              void* d_out, int out_size, void* d_ws, size_t ws_size,
                              hipStream_t stream)
{
  const float* hidden = (const float*)d_in[0];   // [2048][2048] f32
  const float* Wqkv   = (const float*)d_in[1];   // [2048][6144] f32
  const float* bqkv   = (const float*)d_in[2];   // [6144] f32
  const float* Wd     = (const float*)d_in[3];   // [2048][2048] f32
  const float* bd     = (const float*)d_in[4];   // [2048] f32
  float* out = (float*)d_out;                    // [2048][2048] f32

  char* ws = (char*)d_ws;
  u16* Q   = (u16*)(ws);                      //  8 MB  Q row-major
  u16* Kb  = (u16*)(ws + (8ull  << 20));      //  8 MB  K flash tiles
  u16* Vt  = (u16*)(ws + (16ull << 20));      //  8 MB  V flash tiles
  u16* ctx = (u16*)(ws + (24ull << 20));      //  8 MB  ctx panels (128x32)
  char* regA = ws + (32ull << 20);            // overlay region

  const bool fast = ws_size >= (64ull << 20);

  if (fast) {
    u16* hidden_bf = (u16*)(regA);                  // 8 MB panels, then Wd_t
    u16* Wqkv_t    = (u16*)(regA + (8ull << 20));   // 24 MB panels
    u16* Wd_t      = (u16*)(regA);                  // 8 MB panels

    convert_bf16_kernel<<<dim3(4096), 256, 0, stream>>>(hidden, hidden_bf, 2048, 1048576);
    transpose_bf16_kernel<<<dim3(192, 64), 256, 0, stream>>>(Wqkv, Wqkv_t, 2048, 6144);

    gemm_kernel<<<dim3(48, 16, 1), 256, 0, stream>>>(
        hidden_bf, Wqkv_t, 2048, 2048, 2048, 0, 0, /*mode*/0, 0, 0, 0, bqkv,
        Q, Kb, Vt, nullptr);

    rope_kernel<<<dim3(4096), 256, 0, stream>>>(Q, Kb);
    transpose_bf16_kernel<<<dim3(64, 64), 256, 0, stream>>>(Wd, Wd_t, 2048, 2048);

    flash_kernel<<<dim3(16, 32), 256, 0, stream>>>(Q, Kb, Vt, ctx);

    gemm_dense_kernel<<<dim3(32, 16), 256, 0, stream>>>(
        ctx, Wd_t, /*nkb*/64, bd, out);
  } else {
    // fallback: fp32 in-GEMM staging for QKV; dense uses ctx panels + fp32 Wd
    gemm_kernel<<<dim3(48, 16, 1), 256, 0, stream>>>(
        hidden, Wqkv, 2048, 2048, 6144, 0, 0, /*mode*/0, 0, 1, 1, bqkv,
        Q, Kb, Vt, nullptr);
    rope_kernel<<<dim3(4096), 256, 0, stream>>>(Q, Kb);
    flash_kernel<<<dim3(16, 32), 256, 0, stream>>>(Q, Kb, Vt, ctx);
    gemm_kernel<<<dim3(16, 16, 1), 256, 0, stream>>>(
        ctx, Wd, 2048, 2048, 2048, 0, 0, /*mode*/3, 0, 0, 1, bd,
        nullptr, nullptr, nullptr, out);
  }
}

// Round 7
// 292.816 us; speedup vs baseline: 1.0935x; 1.0116x over previous
//
#include <hip/hip_runtime.h>

typedef unsigned short u16;
typedef __attribute__((ext_vector_type(8))) short short8;
typedef __attribute__((ext_vector_type(4))) float floatx4;

#define DEVI static __device__ __forceinline__

DEVI float bf2f(u16 u) {
  union { unsigned u; float f; } x; x.u = ((unsigned)u) << 16; return x.f;
}
DEVI u16 f2bf(float f) {
  union { float f; unsigned u; } x; x.f = f;
  unsigned r = x.u + 0x7fffu + ((x.u >> 16) & 1u);  // RNE
  return (u16)(r >> 16);
}

// async global->LDS, 16 B per lane, wave-uniform LDS base (dest = base + lane*16)
typedef __attribute__((address_space(1))) const void gas_t;
typedef __attribute__((address_space(3))) void las_t;
DEVI void glds16(const void* g, void* l) {
  __builtin_amdgcn_global_load_lds((gas_t*)g, (las_t*)l, 16, 0, 0);
}

#define BM 128
#define BN 128
#define BK 32

// ---- workspace layouts ----
// 128x32 panels (all GEMM operands): tile (rb,kb) contiguous at
//   ((rb*(K/32))+kb)*4096 u16, elem (r,k) -> r*32 + (k&31).
// Q: row-major [head][t][128].
// K flash tiles: elem (h,t,d) ->
//   h*262144 + (t>>6)*8192 + (d>>5)*2048 + (t&63)*32 + (d&31)
// V flash tiles: elem (h,t,d) ->
//   h*262144 + (t>>6)*8192 + ((t&63)>>5)*4096 + d*32 + (t&31)
//
// Lessons pinned: (r3) no transcendentals in register-fat GEMM epilogues ->
// scratch spill. (r1/r2) 256x256 8-phase does not beat m97 here. (r5) BK=64
// regresses. QKV GEMM stays the round-0 m97 structure, 67 us measured.

// Epilogue modes: 0 = QKV (+bias, scatter Q/K/V), 3 = dense (+bias, f32 out)
__global__ __launch_bounds__(256)
void gemm_kernel(const void* __restrict__ Av, const void* __restrict__ Bv,
                 int K, int lda, int ldb,
                 long sAz, long sBz, int mode, int head0, int aF32, int bF32,
                 const float* __restrict__ bias,
                 u16* __restrict__ out0, u16* __restrict__ out1,
                 u16* __restrict__ out2, float* __restrict__ outf)
{
  const int bn = blockIdx.x, bm = blockIdx.y, z = blockIdx.z;
  const int m0 = bm * BM, n0 = bn * BN;
  const int nkb = K >> 5;

  const float* Af = (const float*)Av;
  const u16*   Ab = (const u16*)Av + (long)z * sAz;
  const float* Bf = (const float*)Bv;
  const u16*   Bb = (const u16*)Bv + (long)z * sBz;

  __shared__ __align__(16) u16 As[BM * BK];   // [m][k] bf16
  __shared__ __align__(16) u16 Bs[BN * BK];   // [n][k] bf16

  const int tid  = threadIdx.x;
  const int lane = tid & 63;
  const int wave = tid >> 6;
  const int wm   = (wave & 1) * 64;
  const int wn   = (wave >> 1) * 64;
  const int lr   = lane & 15;
  const int quad = lane >> 4;

  floatx4 acc[4][4];
  #pragma unroll
  for (int i = 0; i < 4; i++)
    #pragma unroll
    for (int j = 0; j < 4; j++)
      acc[i][j] = floatx4{0.f, 0.f, 0.f, 0.f};

  for (int kb = 0; kb < nkb; kb++) {
    const int k0 = kb * BK;
    __syncthreads();
    if (aF32) {
      #pragma unroll
      for (int L = tid; L < 1024; L += 256) {
        int row = L >> 3, c4 = (L & 7) * 4;
        float4 v = *(const float4*)(Af + (long)(m0 + row) * lda + k0 + c4);
        ushort4 p;
        p.x = f2bf(v.x); p.y = f2bf(v.y); p.z = f2bf(v.z); p.w = f2bf(v.w);
        *(ushort4*)(&As[row * BK + c4]) = p;
      }
    } else {
      const u16* At = Ab + ((long)bm * nkb + kb) * 4096;
      #pragma unroll
      for (int it = 0; it < 2; it++) {
        int Cb = (wave * 2 + it) * 64;
        glds16(At + (long)(Cb + lane) * 8, &As[Cb * 8]);
      }
    }
    if (bF32) {
      #pragma unroll
      for (int L = tid; L < 1024; L += 256) {
        int kr = L >> 5, n4 = (L & 31) * 4;
        float4 v = *(const float4*)(Bf + (long)(k0 + kr) * ldb + n0 + n4);
        Bs[(n4 + 0) * BK + kr] = f2bf(v.x);
        Bs[(n4 + 1) * BK + kr] = f2bf(v.y);
        Bs[(n4 + 2) * BK + kr] = f2bf(v.z);
        Bs[(n4 + 3) * BK + kr] = f2bf(v.w);
      }
    } else {
      const u16* Bt = Bb + ((long)bn * nkb + kb) * 4096;
      #pragma unroll
      for (int it = 0; it < 2; it++) {
        int Cb = (wave * 2 + it) * 64;
        glds16(Bt + (long)(Cb + lane) * 8, &Bs[Cb * 8]);
      }
    }
    __syncthreads();

    short8 af[4], bf[4];
    #pragma unroll
    for (int i = 0; i < 4; i++)
      af[i] = *(const short8*)(&As[(wm + i * 16 + lr) * BK + quad * 8]);
    #pragma unroll
    for (int j = 0; j < 4; j++)
      bf[j] = *(const short8*)(&Bs[(wn + j * 16 + lr) * BK + quad * 8]);
    #pragma unroll
    for (int i = 0; i < 4; i++)
      #pragma unroll
      for (int j = 0; j < 4; j++)
        acc[i][j] = __builtin_amdgcn_mfma_f32_16x16x32_bf16(af[i], bf[j], acc[i][j], 0, 0, 0);
  }

  // epilogue: C/D layout col=lane&15, row=quad*4+reg. In mode 0 each
  // 128-col block is purely Q, K, or V (384 = 3*128) with one head.
  #pragma unroll
  for (int i = 0; i < 4; i++) {
    #pragma unroll
    for (int j = 0; j < 4; j++) {
      const int col = n0 + wn + j * 16 + lr;
      const int t0  = m0 + wm + i * 16 + quad * 4;   // row for r=0
      if (mode == 0) {
        int head = col / 384;
        int w = col - head * 384;
        long hbase = (long)head * 262144;
        float b = bias[col];
        if (w < 128) {          // Q row-major, pre-scaled by 1/sqrt(128)
          #pragma unroll
          for (int r = 0; r < 4; r++)
            out0[hbase + (long)(t0 + r) * 128 + w] =
                f2bf((acc[i][j][r] + b) * 0.08838834764831845f);
        } else if (w < 256) {   // K flash tiles (t-major inside chunk)
          int d = w - 128;
          long base = hbase + (long)(t0 >> 6) * 8192 + (d >> 5) * 2048 + (d & 31);
          #pragma unroll
          for (int r = 0; r < 4; r++)
            out1[base + ((t0 & 63) + r) * 32] = f2bf(acc[i][j][r] + b);
        } else {                // V flash tiles: r-contiguous -> ushort4
          int d = w - 256;
          long base = hbase + (long)(t0 >> 6) * 8192 + ((t0 & 63) >> 5) * 4096
                    + d * 32 + (t0 & 31);
          ushort4 p;
          p.x = f2bf(acc[i][j][0] + b);
          p.y = f2bf(acc[i][j][1] + b);
          p.z = f2bf(acc[i][j][2] + b);
          p.w = f2bf(acc[i][j][3] + b);
          *(ushort4*)(&out2[base]) = p;
        }
      } else {
        float b = bias[col];
        #pragma unroll
        for (int r = 0; r < 4; r++)
          outf[(long)(t0 + r) * 2048 + col] = acc[i][j][r] + b;
      }
    }
  }
}

// ---------------- dense 128x64 GEMM, 2 WG/CU (ctx @ Wd_t -> out f32) -------
__global__ __launch_bounds__(256)
void gemm_dense_kernel(const u16* __restrict__ Ap, const u16* __restrict__ Bp,
                       int nkb, const float* __restrict__ bias,
                       float* __restrict__ outf)
{
  const int bn = blockIdx.x, bm = blockIdx.y;
  const int m0 = bm << 7, n0 = bn << 6;

  __shared__ __align__(16) u16 As[128 * 32];   // 8 KB
  __shared__ __align__(16) u16 Bs[64 * 32];    // 4 KB

  const int tid  = threadIdx.x;
  const int lane = tid & 63;
  const int wave = tid >> 6;
  const int wm   = (wave & 1) * 64;
  const int wn   = (wave >> 1) * 32;
  const int lr   = lane & 15;
  const int quad = lane >> 4;

  floatx4 acc[4][2];
  #pragma unroll
  for (int i = 0; i < 4; i++)
    #pragma unroll
    for (int j = 0; j < 2; j++)
      acc[i][j] = floatx4{0.f, 0.f, 0.f, 0.f};

  const u16* Bbase = Bp + (long)(n0 >> 7) * nkb * 4096 + (long)(n0 & 127) * 32;

  for (int kb = 0; kb < nkb; kb++) {
    __syncthreads();
    const u16* At = Ap + ((long)bm * nkb + kb) * 4096;
    const u16* Bt = Bbase + (long)kb * 4096;
    #pragma unroll
    for (int it = 0; it < 2; it++) {
      int c = wave * 2 + it;
      glds16(At + c * 512 + lane * 8, &As[c * 512]);
    }
    glds16(Bt + wave * 512 + lane * 8, &Bs[wave * 512]);
    __syncthreads();

    short8 af[4], bf[2];
    #pragma unroll
    for (int i = 0; i < 4; i++)
      af[i] = *(const short8*)(&As[(wm + i * 16 + lr) * 32 + quad * 8]);
    #pragma unroll
    for (int j = 0; j < 2; j++)
      bf[j] = *(const short8*)(&Bs[(wn + j * 16 + lr) * 32 + quad * 8]);
    #pragma unroll
    for (int i = 0; i < 4; i++)
      #pragma unroll
      for (int j = 0; j < 2; j++)
        acc[i][j] = __builtin_amdgcn_mfma_f32_16x16x32_bf16(af[i], bf[j], acc[i][j], 0, 0, 0);
  }

  #pragma unroll
  for (int i = 0; i < 4; i++) {
    #pragma unroll
    for (int j = 0; j < 2; j++) {
      const int col = n0 + wn + j * 16 + lr;
      const int t0  = m0 + wm + i * 16 + quad * 4;
      float b = bias[col];
      #pragma unroll
      for (int r = 0; r < 4; r++)
        outf[(long)(t0 + r) * 2048 + col] = acc[i][j][r] + b;
    }
  }
}

// ---------------- fused flash attention, v7 (MFMA row-sum) -----------------
// v6 + replace the per-tile 16x dependent __shfl_xor row-sum (4-deep latency
// chain x 4 rows, ~400-500 cy/tile) with a ones-B-fragment MFMA in the PV
// step: l_acc = mfma(pa, ones, l_acc). Output layout row=quad*4+r means each
// lane holds l for exactly its own rows -> zero cross-lane traffic. l is now
// computed from the SAME bf16 P used for PV, so normalization error
// partially cancels. Masked lanes have P==0 -> contribute 0 to O and l.
__global__ __launch_bounds__(256, 2)
void flash_kernel(const u16* __restrict__ Qg, const u16* __restrict__ Kg,
                  const u16* __restrict__ Vg, u16* __restrict__ ctx)
{
  const int head = blockIdx.x, slot = blockIdx.y;
  const int qb   = (slot < 16) ? slot : 47 - slot;
  const int nkt  = qb + 1;               // 64-row K/V tiles
  const long HS  = 2048L * 128;
  const u16* Qh = Qg + (long)head * HS;
  const u16* Kh = Kg + (long)head * HS;  // flash-tile layout
  const u16* Vh = Vg + (long)head * HS;  // flash-tile layout

  __shared__ __align__(16) u16 k_s[2][8192];   // 2 x 16 KB  [kt][n][32]
  __shared__ __align__(16) u16 v_s[2][8192];   // 2 x 16 KB  [kt2][d][32]
  __shared__ __align__(16) u16 p_s[4 * 1088];  // 8.5 KB, per-wave 16 x stride-68

  const int tid  = threadIdx.x;
  const int lane = tid & 63, wv = tid >> 6;
  const int lr   = lane & 15, quad = lane >> 4;
  const int qs   = qb * 64 + wv * 16;
  const int pbase = wv * 1088;

  short8 qf[4];
  #pragma unroll
  for (int kt = 0; kt < 4; kt++)
    qf[kt] = *(const short8*)(Qh + (long)(qs + lr) * 128 + kt * 32 + quad * 8);

  short8 vones;
  #pragma unroll
  for (int k = 0; k < 8; k++) vones[k] = (short)0x3F80;  // bf16 1.0

  floatx4 l_acc = floatx4{0.f, 0.f, 0.f, 0.f};

  floatx4 o[8];
  #pragma unroll
  for (int j = 0; j < 8; j++) o[j] = floatx4{0.f, 0.f, 0.f, 0.f};

  // prologue: stage tile 0 into buffer 0 (8 glds16/wave, contiguous bursts)
  #pragma unroll
  for (int it = 0; it < 4; it++) {
    int Cb = (wv * 4 + it) * 64;
    glds16(Kh + (long)(Cb + lane) * 8, &k_s[0][Cb * 8]);
    glds16(Vh + (long)(Cb + lane) * 8, &v_s[0][Cb * 8]);
  }

  for (int kb = 0; kb < nkt; kb++) {
    const int cur = kb & 1;
    __syncthreads();                     // drains own DMA -> buf[cur] ready
    if (kb + 1 < nkt) {                  // prefetch tile kb+1 into buf[cur^1]
      const u16* Kt = Kh + (long)(kb + 1) * 8192;
      const u16* Vt = Vh + (long)(kb + 1) * 8192;
      #pragma unroll
      for (int it = 0; it < 4; it++) {
        int Cb = (wv * 4 + it) * 64;
        glds16(Kt + (long)(Cb + lane) * 8, &k_s[cur ^ 1][Cb * 8]);
        glds16(Vt + (long)(Cb + lane) * 8, &v_s[cur ^ 1][Cb * 8]);
      }
    }

    // S = Q K^T : strip 16 rows x 64 cols
    floatx4 sa[4];
    #pragma unroll
    for (int j = 0; j < 4; j++) sa[j] = floatx4{0.f, 0.f, 0.f, 0.f};
    __builtin_amdgcn_s_setprio(1);
    #pragma unroll
    for (int kt = 0; kt < 4; kt++) {
      #pragma unroll
      for (int j = 0; j < 4; j++) {
        short8 bf = *(const short8*)(&k_s[cur][kt * 2048 + (j * 16 + lr) * 32 + quad * 8]);
        sa[j] = __builtin_amdgcn_mfma_f32_16x16x32_bf16(qf[kt], bf, sa[j], 0, 0, 0);
      }
    }
    __builtin_amdgcn_s_setprio(0);

    if (kb == nkt - 1) {                 // causal mask, last tile only
      #pragma unroll
      for (int j = 0; j < 4; j++)
        #pragma unroll
        for (int r = 0; r < 4; r++) {
          int cg = kb * 64 + j * 16 + lr;
          int rg = qs + quad * 4 + r;
          if (cg > rg) sa[j][r] = -1e30f;
        }
    }

    // static-shift softmax: P = exp(S - 8) -> bf16 -> LDS. No row-sum here
    // (MFMA ones-column in PV computes it). Masked lanes underflow to 0.
    #pragma unroll
    for (int r = 0; r < 4; r++) {
      #pragma unroll
      for (int j = 0; j < 4; j++) {
        float e = __expf(sa[j][r] - 8.f);
        p_s[pbase + (quad * 4 + r) * 68 + j * 16 + lr] = f2bf(e);
      }
    }

    // PV: O += P x V, l_acc += P x 1 (same-wave P write->read, no barrier)
    __builtin_amdgcn_s_setprio(1);
    #pragma unroll
    for (int kt2 = 0; kt2 < 2; kt2++) {
      short8 pa = *(const short8*)(&p_s[pbase + lr * 68 + kt2 * 32 + quad * 8]);
      l_acc = __builtin_amdgcn_mfma_f32_16x16x32_bf16(pa, vones, l_acc, 0, 0, 0);
      #pragma unroll
      for (int j = 0; j < 8; j++) {
        short8 vb = *(const short8*)(&v_s[cur][kt2 * 4096 + (j * 16 + lr) * 32 + quad * 8]);
        o[j] = __builtin_amdgcn_mfma_f32_16x16x32_bf16(pa, vb, o[j], 0, 0, 0);
      }
    }
    __builtin_amdgcn_s_setprio(0);
  } // kb

  // epilogue -> ctx PANELS: element (row, c), c = head*128 + j*16 + lr.
  // l_acc[r] = row-sum of P for row quad*4+r (every lane holds its own rows).
  #pragma unroll
  for (int r = 0; r < 4; r++) {
    float inv = 1.f / l_acc[r];
    int row = qs + quad * 4 + r;
    long prow = ((long)(row >> 7) * 64) * 4096 + (row & 127) * 32;
    #pragma unroll
    for (int j = 0; j < 8; j++) {
      int c = head * 128 + j * 16 + lr;
      ctx[prow + (long)(c >> 5) * 4096 + (c & 31)] = f2bf(o[j][r] * inv);
    }
  }
}

// ---------------- fused prep: convert(hidden) + transpose(Wqkv) ------------
// Block-range partition (divergence at WG granularity only):
//   blocks [0, 4096)      : hidden f32 [2048][2048] -> bf16 128x32 panels
//   blocks [4096, 16384)  : Wqkv f32 [2048][6144] -> bf16 panels of Wqkv^T
// Saves one dispatch (+its graph-node gap) vs separate kernels.
__global__ __launch_bounds__(256)
void prep_kernel(const float* __restrict__ hidden, u16* __restrict__ hidden_bf,
                 const float* __restrict__ Wqkv, u16* __restrict__ Wqkv_t)
{
  const int b = blockIdx.x;
  if (b < 4096) {
    // ---- convert: float4/thread, K=2048
    long i = (long)b * 256 + threadIdx.x;
    float4 v = ((const float4*)hidden)[i];
    ushort4 p;
    p.x = f2bf(v.x); p.y = f2bf(v.y); p.z = f2bf(v.z); p.w = f2bf(v.w);
    long e = i * 4;
    int row = (int)(e >> 11), k = (int)(e & 2047);
    long d = ((long)(row >> 7) * 64 + (k >> 5)) * 4096
           + (row & 127) * 32 + (k & 31);
    *(ushort4*)(&hidden_bf[d]) = p;
  } else {
    // ---- transpose Wqkv: K=2048, N=6144, 32x32 tiles, coalesced writes
    const int t  = b - 4096;             // 0..12287
    const int n0 = (t % 192) * 32;
    const int k0 = (t / 192) * 32;
    __shared__ float tt[32][33];
    int tx = threadIdx.x & 31, ty = threadIdx.x >> 5;
    #pragma unroll
    for (int i = 0; i < 4; i++)
      tt[ty + i * 8][tx] = Wqkv[(long)(k0 + ty + i * 8) * 6144 + n0 + tx];
    __syncthreads();
    const int w  = threadIdx.x;
    const int np = w >> 3;           // n within tile
    const int kp = (w & 7) * 4;      // k within tile (quad)
    ushort4 p;
    p.x = f2bf(tt[kp + 0][np]);
    p.y = f2bf(tt[kp + 1][np]);
    p.z = f2bf(tt[kp + 2][np]);
    p.w = f2bf(tt[kp + 3][np]);
    const int n = n0 + np, k = k0 + kp;
    long d = ((long)(n >> 7) * 64 + (k >> 5)) * 4096 + (n & 127) * 32 + (k & 31);
    *(ushort4*)(&Wqkv_t[d]) = p;
  }
}

// fp32 [K][N] -> bf16 128-PANELS of the [N][K] transpose. 32x32 tiles,
// coalesced write phase (WG emits one contiguous 2048 B panel block).
__global__ __launch_bounds__(256)
void transpose_bf16_kernel(const float* __restrict__ in, u16* __restrict__ out,
                           int K, int N)
{
  __shared__ float t[32][33];
  int n0 = blockIdx.x * 32, k0 = blockIdx.y * 32;
  int tx = threadIdx.x & 31, ty = threadIdx.x >> 5;
  #pragma unroll
  for (int i = 0; i < 4; i++)
    t[ty + i * 8][tx] = in[(long)(k0 + ty + i * 8) * N + n0 + tx];  // t[k'][n']
  __syncthreads();
  const int nkb = K >> 5;
  const int w  = threadIdx.x;
  const int np = w >> 3;
  const int kp = (w & 7) * 4;
  ushort4 p;
  p.x = f2bf(t[kp + 0][np]);
  p.y = f2bf(t[kp + 1][np]);
  p.z = f2bf(t[kp + 2][np]);
  p.w = f2bf(t[kp + 3][np]);
  const int n = n0 + np, k = k0 + kp;
  long d = ((long)(n >> 7) * nkb + (k >> 5)) * 4096 + (n & 127) * 32 + (k & 31);
  *(ushort4*)(&out[d]) = p;
}

// RoPE in-place on first 32 dims of Q (row-major) and K (flash tiles).
__global__ __launch_bounds__(256)
void rope_kernel(u16* __restrict__ Q, u16* __restrict__ K)
{
  int idx = blockIdx.x * 256 + threadIdx.x;
  int i = idx & 15;
  int s = (idx >> 4) & 2047;
  int head = (idx >> 15) & 15;
  int isK = (idx >> 19);
  float inv_freq = exp2f(-(float)i * 0.83048202372184058696f); // 10000^(-i/16)
  float ang = (float)s * inv_freq;
  float c = cosf(ang), sn = sinf(ang);
  long b0, b1;
  u16* buf;
  if (isK) {
    buf = K;
    long base = (long)head * 262144 + (long)(s >> 6) * 8192 + (s & 63) * 32;
    b0 = base + i;         // d = i      (kt=0 chunk)
    b1 = base + i + 16;    // d = i+16
  } else {
    buf = Q;
    long base = ((long)head * 2048 + s) * 128;
    b0 = base + i;
    b1 = base + i + 16;
  }
  float x1 = bf2f(buf[b0]);
  float x2 = bf2f(buf[b1]);
  buf[b0] = f2bf(x1 * c - x2 * sn);
  buf[b1] = f2bf(x2 * c + x1 * sn);
}

extern "C" void kernel_launch(void* const* d_in, const int* in_sizes, int n_in,
                              void* d_out, int out_size, void* d_ws, size_t ws_size,
                              hipStream_t stream)
{
  const float* hidden = (const float*)d_in[0];   // [2048][2048] f32
  const float* Wqkv   = (const float*)d_in[1];   // [2048][6144] f32
  const float* bqkv   = (const float*)d_in[2];   // [6144] f32
  const float* Wd     = (const float*)d_in[3];   // [2048][2048] f32
  const float* bd     = (const float*)d_in[4];   // [2048] f32
  float* out = (float*)d_out;                    // [2048][2048] f32

  char* ws = (char*)d_ws;
  u16* Q   = (u16*)(ws);                      //  8 MB  Q row-major
  u16* Kb  = (u16*)(ws + (8ull  << 20));      //  8 MB  K flash tiles
  u16* Vt  = (u16*)(ws + (16ull << 20));      //  8 MB  V flash tiles
  u16* ctx = (u16*)(ws + (24ull << 20));      //  8 MB  ctx panels (128x32)
  char* regA = ws + (32ull << 20);            // overlay region

  const bool fast = ws_size >= (64ull << 20);

  if (fast) {
    u16* hidden_bf = (u16*)(regA);                  // 8 MB panels, then Wd_t
    u16* Wqkv_t    = (u16*)(regA + (8ull << 20));   // 24 MB panels
    u16* Wd_t      = (u16*)(regA);                  // 8 MB panels

    prep_kernel<<<dim3(16384), 256, 0, stream>>>(hidden, hidden_bf, Wqkv, Wqkv_t);

    gemm_kernel<<<dim3(48, 16, 1), 256, 0, stream>>>(
        hidden_bf, Wqkv_t, 2048, 2048, 2048, 0, 0, /*mode*/0, 0, 0, 0, bqkv,
        Q, Kb, Vt, nullptr);

    rope_kernel<<<dim3(4096), 256, 0, stream>>>(Q, Kb);
    transpose_bf16_kernel<<<dim3(64, 64), 256, 0, stream>>>(Wd, Wd_t, 2048, 2048);

    flash_kernel<<<dim3(16, 32), 256, 0, stream>>>(Q, Kb, Vt, ctx);

    gemm_dense_kernel<<<dim3(32, 16), 256, 0, stream>>>(
        ctx, Wd_t, /*nkb*/64, bd, out);
  } else {
    // fallback: fp32 in-GEMM staging for QKV; dense uses ctx panels + fp32 Wd
    gemm_kernel<<<dim3(48, 16, 1), 256, 0, stream>>>(
        hidden, Wqkv, 2048, 2048, 6144, 0, 0, /*mode*/0, 0, 1, 1, bqkv,
        Q, Kb, Vt, nullptr);
    rope_kernel<<<dim3(4096), 256, 0, stream>>>(Q, Kb);
    flash_kernel<<<dim3(16, 32), 256, 0, stream>>>(Q, Kb, Vt, ctx);
    gemm_kernel<<<dim3(16, 16, 1), 256, 0, stream>>>(
        ctx, Wd, 2048, 2048, 2048, 0, 0, /*mode*/3, 0, 0, 1, bd,
        nullptr, nullptr, nullptr, out);
  }
}

// Round 8
// 289.424 us; speedup vs baseline: 1.1063x; 1.0117x over previous
//
#include <hip/hip_runtime.h>

typedef unsigned short u16;
typedef __attribute__((ext_vector_type(8))) short short8;
typedef __attribute__((ext_vector_type(4))) float floatx4;

#define DEVI static __device__ __forceinline__

DEVI float bf2f(u16 u) {
  union { unsigned u; float f; } x; x.u = ((unsigned)u) << 16; return x.f;
}
DEVI u16 f2bf(float f) {
  union { float f; unsigned u; } x; x.f = f;
  unsigned r = x.u + 0x7fffu + ((x.u >> 16) & 1u);  // RNE
  return (u16)(r >> 16);
}

// async global->LDS, 16 B per lane, wave-uniform LDS base (dest = base + lane*16)
typedef __attribute__((address_space(1))) const void gas_t;
typedef __attribute__((address_space(3))) void las_t;
DEVI void glds16(const void* g, void* l) {
  __builtin_amdgcn_global_load_lds((gas_t*)g, (las_t*)l, 16, 0, 0);
}

#define BM 128
#define BN 128
#define BK 32

// ---- workspace layouts ----
// 128x32 panels (all GEMM operands): tile (rb,kb) contiguous at
//   ((rb*(K/32))+kb)*4096 u16, elem (r,k) -> r*32 + (k&31).
// Q: row-major [head][t][128].
// K flash tiles: elem (h,t,d) ->
//   h*262144 + (t>>6)*8192 + (d>>5)*2048 + (t&63)*32 + (d&31)
// V flash tiles: elem (h,t,d) ->
//   h*262144 + (t>>6)*8192 + ((t&63)>>5)*4096 + d*32 + (t&31)
//
// Lessons pinned: (r3) no transcendentals in register-fat GEMM epilogues ->
// scratch spill. (r1/r2) 256x256 8-phase does not beat m97 here. (r5) BK=64
// regresses. (r7) QKV bank conflicts cost ~1.3x on LDS pipe, hidden under
// MFMA; XOR can't fix 64B-row period at BK=32 — leave. QKV GEMM stays the
// round-0 m97 structure, 67 us measured. Dispatch-count is the live lever.

// Epilogue modes: 0 = QKV (+bias, scatter Q/K/V), 3 = dense (+bias, f32 out)
__global__ __launch_bounds__(256)
void gemm_kernel(const void* __restrict__ Av, const void* __restrict__ Bv,
                 int K, int lda, int ldb,
                 long sAz, long sBz, int mode, int head0, int aF32, int bF32,
                 const float* __restrict__ bias,
                 u16* __restrict__ out0, u16* __restrict__ out1,
                 u16* __restrict__ out2, float* __restrict__ outf)
{
  const int bn = blockIdx.x, bm = blockIdx.y, z = blockIdx.z;
  const int m0 = bm * BM, n0 = bn * BN;
  const int nkb = K >> 5;

  const float* Af = (const float*)Av;
  const u16*   Ab = (const u16*)Av + (long)z * sAz;
  const float* Bf = (const float*)Bv;
  const u16*   Bb = (const u16*)Bv + (long)z * sBz;

  __shared__ __align__(16) u16 As[BM * BK];   // [m][k] bf16
  __shared__ __align__(16) u16 Bs[BN * BK];   // [n][k] bf16

  const int tid  = threadIdx.x;
  const int lane = tid & 63;
  const int wave = tid >> 6;
  const int wm   = (wave & 1) * 64;
  const int wn   = (wave >> 1) * 64;
  const int lr   = lane & 15;
  const int quad = lane >> 4;

  floatx4 acc[4][4];
  #pragma unroll
  for (int i = 0; i < 4; i++)
    #pragma unroll
    for (int j = 0; j < 4; j++)
      acc[i][j] = floatx4{0.f, 0.f, 0.f, 0.f};

  for (int kb = 0; kb < nkb; kb++) {
    const int k0 = kb * BK;
    __syncthreads();
    if (aF32) {
      #pragma unroll
      for (int L = tid; L < 1024; L += 256) {
        int row = L >> 3, c4 = (L & 7) * 4;
        float4 v = *(const float4*)(Af + (long)(m0 + row) * lda + k0 + c4);
        ushort4 p;
        p.x = f2bf(v.x); p.y = f2bf(v.y); p.z = f2bf(v.z); p.w = f2bf(v.w);
        *(ushort4*)(&As[row * BK + c4]) = p;
      }
    } else {
      const u16* At = Ab + ((long)bm * nkb + kb) * 4096;
      #pragma unroll
      for (int it = 0; it < 2; it++) {
        int Cb = (wave * 2 + it) * 64;
        glds16(At + (long)(Cb + lane) * 8, &As[Cb * 8]);
      }
    }
    if (bF32) {
      #pragma unroll
      for (int L = tid; L < 1024; L += 256) {
        int kr = L >> 5, n4 = (L & 31) * 4;
        float4 v = *(const float4*)(Bf + (long)(k0 + kr) * ldb + n0 + n4);
        Bs[(n4 + 0) * BK + kr] = f2bf(v.x);
        Bs[(n4 + 1) * BK + kr] = f2bf(v.y);
        Bs[(n4 + 2) * BK + kr] = f2bf(v.z);
        Bs[(n4 + 3) * BK + kr] = f2bf(v.w);
      }
    } else {
      const u16* Bt = Bb + ((long)bn * nkb + kb) * 4096;
      #pragma unroll
      for (int it = 0; it < 2; it++) {
        int Cb = (wave * 2 + it) * 64;
        glds16(Bt + (long)(Cb + lane) * 8, &Bs[Cb * 8]);
      }
    }
    __syncthreads();

    short8 af[4], bf[4];
    #pragma unroll
    for (int i = 0; i < 4; i++)
      af[i] = *(const short8*)(&As[(wm + i * 16 + lr) * BK + quad * 8]);
    #pragma unroll
    for (int j = 0; j < 4; j++)
      bf[j] = *(const short8*)(&Bs[(wn + j * 16 + lr) * BK + quad * 8]);
    #pragma unroll
    for (int i = 0; i < 4; i++)
      #pragma unroll
      for (int j = 0; j < 4; j++)
        acc[i][j] = __builtin_amdgcn_mfma_f32_16x16x32_bf16(af[i], bf[j], acc[i][j], 0, 0, 0);
  }

  // epilogue: C/D layout col=lane&15, row=quad*4+reg. In mode 0 each
  // 128-col block is purely Q, K, or V (384 = 3*128) with one head.
  #pragma unroll
  for (int i = 0; i < 4; i++) {
    #pragma unroll
    for (int j = 0; j < 4; j++) {
      const int col = n0 + wn + j * 16 + lr;
      const int t0  = m0 + wm + i * 16 + quad * 4;   // row for r=0
      if (mode == 0) {
        int head = col / 384;
        int w = col - head * 384;
        long hbase = (long)head * 262144;
        float b = bias[col];
        if (w < 128) {          // Q row-major, pre-scaled by 1/sqrt(128)
          #pragma unroll
          for (int r = 0; r < 4; r++)
            out0[hbase + (long)(t0 + r) * 128 + w] =
                f2bf((acc[i][j][r] + b) * 0.08838834764831845f);
        } else if (w < 256) {   // K flash tiles (t-major inside chunk)
          int d = w - 128;
          long base = hbase + (long)(t0 >> 6) * 8192 + (d >> 5) * 2048 + (d & 31);
          #pragma unroll
          for (int r = 0; r < 4; r++)
            out1[base + ((t0 & 63) + r) * 32] = f2bf(acc[i][j][r] + b);
        } else {                // V flash tiles: r-contiguous -> ushort4
          int d = w - 256;
          long base = hbase + (long)(t0 >> 6) * 8192 + ((t0 & 63) >> 5) * 4096
                    + d * 32 + (t0 & 31);
          ushort4 p;
          p.x = f2bf(acc[i][j][0] + b);
          p.y = f2bf(acc[i][j][1] + b);
          p.z = f2bf(acc[i][j][2] + b);
          p.w = f2bf(acc[i][j][3] + b);
          *(ushort4*)(&out2[base]) = p;
        }
      } else {
        float b = bias[col];
        #pragma unroll
        for (int r = 0; r < 4; r++)
          outf[(long)(t0 + r) * 2048 + col] = acc[i][j][r] + b;
      }
    }
  }
}

// ---------------- dense 128x64 GEMM, 2 WG/CU (ctx @ Wd_t -> out f32) -------
__global__ __launch_bounds__(256)
void gemm_dense_kernel(const u16* __restrict__ Ap, const u16* __restrict__ Bp,
                       int nkb, const float* __restrict__ bias,
                       float* __restrict__ outf)
{
  const int bn = blockIdx.x, bm = blockIdx.y;
  const int m0 = bm << 7, n0 = bn << 6;

  __shared__ __align__(16) u16 As[128 * 32];   // 8 KB
  __shared__ __align__(16) u16 Bs[64 * 32];    // 4 KB

  const int tid  = threadIdx.x;
  const int lane = tid & 63;
  const int wave = tid >> 6;
  const int wm   = (wave & 1) * 64;
  const int wn   = (wave >> 1) * 32;
  const int lr   = lane & 15;
  const int quad = lane >> 4;

  floatx4 acc[4][2];
  #pragma unroll
  for (int i = 0; i < 4; i++)
    #pragma unroll
    for (int j = 0; j < 2; j++)
      acc[i][j] = floatx4{0.f, 0.f, 0.f, 0.f};

  const u16* Bbase = Bp + (long)(n0 >> 7) * nkb * 4096 + (long)(n0 & 127) * 32;

  for (int kb = 0; kb < nkb; kb++) {
    __syncthreads();
    const u16* At = Ap + ((long)bm * nkb + kb) * 4096;
    const u16* Bt = Bbase + (long)kb * 4096;
    #pragma unroll
    for (int it = 0; it < 2; it++) {
      int c = wave * 2 + it;
      glds16(At + c * 512 + lane * 8, &As[c * 512]);
    }
    glds16(Bt + wave * 512 + lane * 8, &Bs[wave * 512]);
    __syncthreads();

    short8 af[4], bf[2];
    #pragma unroll
    for (int i = 0; i < 4; i++)
      af[i] = *(const short8*)(&As[(wm + i * 16 + lr) * 32 + quad * 8]);
    #pragma unroll
    for (int j = 0; j < 2; j++)
      bf[j] = *(const short8*)(&Bs[(wn + j * 16 + lr) * 32 + quad * 8]);
    #pragma unroll
    for (int i = 0; i < 4; i++)
      #pragma unroll
      for (int j = 0; j < 2; j++)
        acc[i][j] = __builtin_amdgcn_mfma_f32_16x16x32_bf16(af[i], bf[j], acc[i][j], 0, 0, 0);
  }

  #pragma unroll
  for (int i = 0; i < 4; i++) {
    #pragma unroll
    for (int j = 0; j < 2; j++) {
      const int col = n0 + wn + j * 16 + lr;
      const int t0  = m0 + wm + i * 16 + quad * 4;
      float b = bias[col];
      #pragma unroll
      for (int r = 0; r < 4; r++)
        outf[(long)(t0 + r) * 2048 + col] = acc[i][j][r] + b;
    }
  }
}

// ---------------- fused flash attention, v7 (MFMA row-sum) -----------------
// Row-sum via ones-B-fragment MFMA in the PV step: l_acc = mfma(pa, ones,
// l_acc); output layout row=quad*4+r -> each lane holds l for its own rows,
// zero cross-lane. l computed from the SAME bf16 P used for PV. Masked
// lanes have P==0 -> contribute 0 to O and l.
__global__ __launch_bounds__(256, 2)
void flash_kernel(const u16* __restrict__ Qg, const u16* __restrict__ Kg,
                  const u16* __restrict__ Vg, u16* __restrict__ ctx)
{
  const int head = blockIdx.x, slot = blockIdx.y;
  const int qb   = (slot < 16) ? slot : 47 - slot;
  const int nkt  = qb + 1;               // 64-row K/V tiles
  const long HS  = 2048L * 128;
  const u16* Qh = Qg + (long)head * HS;
  const u16* Kh = Kg + (long)head * HS;  // flash-tile layout
  const u16* Vh = Vg + (long)head * HS;  // flash-tile layout

  __shared__ __align__(16) u16 k_s[2][8192];   // 2 x 16 KB  [kt][n][32]
  __shared__ __align__(16) u16 v_s[2][8192];   // 2 x 16 KB  [kt2][d][32]
  __shared__ __align__(16) u16 p_s[4 * 1088];  // 8.5 KB, per-wave 16 x stride-68

  const int tid  = threadIdx.x;
  const int lane = tid & 63, wv = tid >> 6;
  const int lr   = lane & 15, quad = lane >> 4;
  const int qs   = qb * 64 + wv * 16;
  const int pbase = wv * 1088;

  short8 qf[4];
  #pragma unroll
  for (int kt = 0; kt < 4; kt++)
    qf[kt] = *(const short8*)(Qh + (long)(qs + lr) * 128 + kt * 32 + quad * 8);

  short8 vones;
  #pragma unroll
  for (int k = 0; k < 8; k++) vones[k] = (short)0x3F80;  // bf16 1.0

  floatx4 l_acc = floatx4{0.f, 0.f, 0.f, 0.f};

  floatx4 o[8];
  #pragma unroll
  for (int j = 0; j < 8; j++) o[j] = floatx4{0.f, 0.f, 0.f, 0.f};

  // prologue: stage tile 0 into buffer 0 (8 glds16/wave, contiguous bursts)
  #pragma unroll
  for (int it = 0; it < 4; it++) {
    int Cb = (wv * 4 + it) * 64;
    glds16(Kh + (long)(Cb + lane) * 8, &k_s[0][Cb * 8]);
    glds16(Vh + (long)(Cb + lane) * 8, &v_s[0][Cb * 8]);
  }

  for (int kb = 0; kb < nkt; kb++) {
    const int cur = kb & 1;
    __syncthreads();                     // drains own DMA -> buf[cur] ready
    if (kb + 1 < nkt) {                  // prefetch tile kb+1 into buf[cur^1]
      const u16* Kt = Kh + (long)(kb + 1) * 8192;
      const u16* Vt = Vh + (long)(kb + 1) * 8192;
      #pragma unroll
      for (int it = 0; it < 4; it++) {
        int Cb = (wv * 4 + it) * 64;
        glds16(Kt + (long)(Cb + lane) * 8, &k_s[cur ^ 1][Cb * 8]);
        glds16(Vt + (long)(Cb + lane) * 8, &v_s[cur ^ 1][Cb * 8]);
      }
    }

    // S = Q K^T : strip 16 rows x 64 cols
    floatx4 sa[4];
    #pragma unroll
    for (int j = 0; j < 4; j++) sa[j] = floatx4{0.f, 0.f, 0.f, 0.f};
    __builtin_amdgcn_s_setprio(1);
    #pragma unroll
    for (int kt = 0; kt < 4; kt++) {
      #pragma unroll
      for (int j = 0; j < 4; j++) {
        short8 bf = *(const short8*)(&k_s[cur][kt * 2048 + (j * 16 + lr) * 32 + quad * 8]);
        sa[j] = __builtin_amdgcn_mfma_f32_16x16x32_bf16(qf[kt], bf, sa[j], 0, 0, 0);
      }
    }
    __builtin_amdgcn_s_setprio(0);

    if (kb == nkt - 1) {                 // causal mask, last tile only
      #pragma unroll
      for (int j = 0; j < 4; j++)
        #pragma unroll
        for (int r = 0; r < 4; r++) {
          int cg = kb * 64 + j * 16 + lr;
          int rg = qs + quad * 4 + r;
          if (cg > rg) sa[j][r] = -1e30f;
        }
    }

    // static-shift softmax: P = exp(S - 8) -> bf16 -> LDS. Row-sum comes
    // from the ones-column MFMA in PV. Masked lanes underflow to 0.
    #pragma unroll
    for (int r = 0; r < 4; r++) {
      #pragma unroll
      for (int j = 0; j < 4; j++) {
        float e = __expf(sa[j][r] - 8.f);
        p_s[pbase + (quad * 4 + r) * 68 + j * 16 + lr] = f2bf(e);
      }
    }

    // PV: O += P x V, l_acc += P x 1 (same-wave P write->read, no barrier)
    __builtin_amdgcn_s_setprio(1);
    #pragma unroll
    for (int kt2 = 0; kt2 < 2; kt2++) {
      short8 pa = *(const short8*)(&p_s[pbase + lr * 68 + kt2 * 32 + quad * 8]);
      l_acc = __builtin_amdgcn_mfma_f32_16x16x32_bf16(pa, vones, l_acc, 0, 0, 0);
      #pragma unroll
      for (int j = 0; j < 8; j++) {
        short8 vb = *(const short8*)(&v_s[cur][kt2 * 4096 + (j * 16 + lr) * 32 + quad * 8]);
        o[j] = __builtin_amdgcn_mfma_f32_16x16x32_bf16(pa, vb, o[j], 0, 0, 0);
      }
    }
    __builtin_amdgcn_s_setprio(0);
  } // kb

  // epilogue -> ctx PANELS: element (row, c), c = head*128 + j*16 + lr.
  #pragma unroll
  for (int r = 0; r < 4; r++) {
    float inv = 1.f / l_acc[r];
    int row = qs + quad * 4 + r;
    long prow = ((long)(row >> 7) * 64) * 4096 + (row & 127) * 32;
    #pragma unroll
    for (int j = 0; j < 8; j++) {
      int c = head * 128 + j * 16 + lr;
      ctx[prow + (long)(c >> 5) * 4096 + (c & 31)] = f2bf(o[j][r] * inv);
    }
  }
}

// ---------------- fused prep: convert(hidden) + transpose(Wqkv) ------------
// Block-range partition (divergence at WG granularity only):
//   blocks [0, 4096)      : hidden f32 [2048][2048] -> bf16 128x32 panels
//   blocks [4096, 16384)  : Wqkv f32 [2048][6144] -> bf16 panels of Wqkv^T
__global__ __launch_bounds__(256)
void prep_kernel(const float* __restrict__ hidden, u16* __restrict__ hidden_bf,
                 const float* __restrict__ Wqkv, u16* __restrict__ Wqkv_t)
{
  const int b = blockIdx.x;
  if (b < 4096) {
    // ---- convert: float4/thread, K=2048
    long i = (long)b * 256 + threadIdx.x;
    float4 v = ((const float4*)hidden)[i];
    ushort4 p;
    p.x = f2bf(v.x); p.y = f2bf(v.y); p.z = f2bf(v.z); p.w = f2bf(v.w);
    long e = i * 4;
    int row = (int)(e >> 11), k = (int)(e & 2047);
    long d = ((long)(row >> 7) * 64 + (k >> 5)) * 4096
           + (row & 127) * 32 + (k & 31);
    *(ushort4*)(&hidden_bf[d]) = p;
  } else {
    // ---- transpose Wqkv: K=2048, N=6144, 32x32 tiles, coalesced writes
    const int t  = b - 4096;             // 0..12287
    const int n0 = (t % 192) * 32;
    const int k0 = (t / 192) * 32;
    __shared__ float tt[32][33];
    int tx = threadIdx.x & 31, ty = threadIdx.x >> 5;
    #pragma unroll
    for (int i = 0; i < 4; i++)
      tt[ty + i * 8][tx] = Wqkv[(long)(k0 + ty + i * 8) * 6144 + n0 + tx];
    __syncthreads();
    const int w  = threadIdx.x;
    const int np = w >> 3;           // n within tile
    const int kp = (w & 7) * 4;      // k within tile (quad)
    ushort4 p;
    p.x = f2bf(tt[kp + 0][np]);
    p.y = f2bf(tt[kp + 1][np]);
    p.z = f2bf(tt[kp + 2][np]);
    p.w = f2bf(tt[kp + 3][np]);
    const int n = n0 + np, k = k0 + kp;
    long d = ((long)(n >> 7) * 64 + (k >> 5)) * 4096 + (n & 127) * 32 + (k & 31);
    *(ushort4*)(&Wqkv_t[d]) = p;
  }
}

// ---------------- fused mid: RoPE(Q,K) + transpose(Wd) ---------------------
// Both run between the QKV GEMM and flash/dense, mutually independent:
//   blocks [0, 4096)    : RoPE in-place on Q (row-major) and K (flash tiles)
//   blocks [4096, 8192) : Wd f32 [2048][2048] -> bf16 panels of Wd^T
// Saves one dispatch + its graph-node boundary.
__global__ __launch_bounds__(256)
void mid_kernel(u16* __restrict__ Q, u16* __restrict__ K,
                const float* __restrict__ Wd, u16* __restrict__ Wd_t)
{
  const int b = blockIdx.x;
  if (b < 4096) {
    // ---- RoPE
    int idx = b * 256 + threadIdx.x;
    int i = idx & 15;
    int s = (idx >> 4) & 2047;
    int head = (idx >> 15) & 15;
    int isK = (idx >> 19);
    float inv_freq = exp2f(-(float)i * 0.83048202372184058696f); // 1e4^(-i/16)
    float ang = (float)s * inv_freq;
    float c = cosf(ang), sn = sinf(ang);
    long b0, b1;
    u16* buf;
    if (isK) {
      buf = K;
      long base = (long)head * 262144 + (long)(s >> 6) * 8192 + (s & 63) * 32;
      b0 = base + i;         // d = i      (kt=0 chunk)
      b1 = base + i + 16;    // d = i+16
    } else {
      buf = Q;
      long base = ((long)head * 2048 + s) * 128;
      b0 = base + i;
      b1 = base + i + 16;
    }
    float x1 = bf2f(buf[b0]);
    float x2 = bf2f(buf[b1]);
    buf[b0] = f2bf(x1 * c - x2 * sn);
    buf[b1] = f2bf(x2 * c + x1 * sn);
  } else {
    // ---- transpose Wd: K=2048, N=2048 (nkb=64), coalesced writes
    const int t  = b - 4096;             // 0..4095
    const int n0 = (t & 63) * 32;
    const int k0 = (t >> 6) * 32;
    __shared__ float tt[32][33];
    int tx = threadIdx.x & 31, ty = threadIdx.x >> 5;
    #pragma unroll
    for (int i = 0; i < 4; i++)
      tt[ty + i * 8][tx] = Wd[(long)(k0 + ty + i * 8) * 2048 + n0 + tx];
    __syncthreads();
    const int w  = threadIdx.x;
    const int np = w >> 3;
    const int kp = (w & 7) * 4;
    ushort4 p;
    p.x = f2bf(tt[kp + 0][np]);
    p.y = f2bf(tt[kp + 1][np]);
    p.z = f2bf(tt[kp + 2][np]);
    p.w = f2bf(tt[kp + 3][np]);
    const int n = n0 + np, k = k0 + kp;
    long d = ((long)(n >> 7) * 64 + (k >> 5)) * 4096 + (n & 127) * 32 + (k & 31);
    *(ushort4*)(&Wd_t[d]) = p;
  }
}

// RoPE standalone (fallback path only).
__global__ __launch_bounds__(256)
void rope_kernel(u16* __restrict__ Q, u16* __restrict__ K)
{
  int idx = blockIdx.x * 256 + threadIdx.x;
  int i = idx & 15;
  int s = (idx >> 4) & 2047;
  int head = (idx >> 15) & 15;
  int isK = (idx >> 19);
  float inv_freq = exp2f(-(float)i * 0.83048202372184058696f); // 10000^(-i/16)
  float ang = (float)s * inv_freq;
  float c = cosf(ang), sn = sinf(ang);
  long b0, b1;
  u16* buf;
  if (isK) {
    buf = K;
    long base = (long)head * 262144 + (long)(s >> 6) * 8192 + (s & 63) * 32;
    b0 = base + i;
    b1 = base + i + 16;
  } else {
    buf = Q;
    long base = ((long)head * 2048 + s) * 128;
    b0 = base + i;
    b1 = base + i + 16;
  }
  float x1 = bf2f(buf[b0]);
  float x2 = bf2f(buf[b1]);
  buf[b0] = f2bf(x1 * c - x2 * sn);
  buf[b1] = f2bf(x2 * c + x1 * sn);
}

extern "C" void kernel_launch(void* const* d_in, const int* in_sizes, int n_in,
                              void* d_out, int out_size, void* d_ws, size_t ws_size,
                              hipStream_t stream)
{
  const float* hidden = (const float*)d_in[0];   // [2048][2048] f32
  const float* Wqkv   = (const float*)d_in[1];   // [2048][6144] f32
  const float* bqkv   = (const float*)d_in[2];   // [6144] f32
  const float* Wd     = (const float*)d_in[3];   // [2048][2048] f32
  const float* bd     = (const float*)d_in[4];   // [2048] f32
  float* out = (float*)d_out;                    // [2048][2048] f32

  char* ws = (char*)d_ws;
  u16* Q   = (u16*)(ws);                      //  8 MB  Q row-major
  u16* Kb  = (u16*)(ws + (8ull  << 20));      //  8 MB  K flash tiles
  u16* Vt  = (u16*)(ws + (16ull << 20));      //  8 MB  V flash tiles
  u16* ctx = (u16*)(ws + (24ull << 20));      //  8 MB  ctx panels (128x32)
  char* regA = ws + (32ull << 20);            // overlay region

  const bool fast = ws_size >= (64ull << 20);

  if (fast) {
    u16* hidden_bf = (u16*)(regA);                  // 8 MB panels, then Wd_t
    u16* Wqkv_t    = (u16*)(regA + (8ull << 20));   // 24 MB panels
    u16* Wd_t      = (u16*)(regA);                  // 8 MB panels

    prep_kernel<<<dim3(16384), 256, 0, stream>>>(hidden, hidden_bf, Wqkv, Wqkv_t);

    gemm_kernel<<<dim3(48, 16, 1), 256, 0, stream>>>(
        hidden_bf, Wqkv_t, 2048, 2048, 2048, 0, 0, /*mode*/0, 0, 0, 0, bqkv,
        Q, Kb, Vt, nullptr);

    mid_kernel<<<dim3(8192), 256, 0, stream>>>(Q, Kb, Wd, Wd_t);

    flash_kernel<<<dim3(16, 32), 256, 0, stream>>>(Q, Kb, Vt, ctx);

    gemm_dense_kernel<<<dim3(32, 16), 256, 0, stream>>>(
        ctx, Wd_t, /*nkb*/64, bd, out);
  } else {
    // fallback: fp32 in-GEMM staging for QKV; dense uses ctx panels + fp32 Wd
    gemm_kernel<<<dim3(48, 16, 1), 256, 0, stream>>>(
        hidden, Wqkv, 2048, 2048, 6144, 0, 0, /*mode*/0, 0, 1, 1, bqkv,
        Q, Kb, Vt, nullptr);
    rope_kernel<<<dim3(4096), 256, 0, stream>>>(Q, Kb);
    flash_kernel<<<dim3(16, 32), 256, 0, stream>>>(Q, Kb, Vt, ctx);
    gemm_kernel<<<dim3(16, 16, 1), 256, 0, stream>>>(
        ctx, Wd, 2048, 2048, 2048, 0, 0, /*mode*/3, 0, 0, 1, bd,
        nullptr, nullptr, nullptr, out);
  }
}